// Round 2
// baseline (435.612 us; speedup 1.0000x reference)
//
#include <hip/hip_runtime.h>
#include <hip/hip_bf16.h>

// B=4, S=2048, D=1024, H=16, HD=64, causal MHA forward, fp32 in/out.
// bf16 MFMA everywhere. 5 kernels: QKV projections, flash attention, out-proj.

#define SLEN 2048
#define DMOD 1024

typedef __attribute__((ext_vector_type(8))) short s16x8;   // 8 bf16 (4 VGPRs)
typedef __attribute__((ext_vector_type(4))) float f32x4;

__device__ __forceinline__ unsigned short f2bf(float f) {
    union { float f; unsigned u; } v; v.f = f;
    unsigned r = v.u + 0x7fffu + ((v.u >> 16) & 1u);   // RNE
    return (unsigned short)(r >> 16);
}
__device__ __forceinline__ unsigned pack2bf(float a, float b) {
    return (unsigned)f2bf(a) | ((unsigned)f2bf(b) << 16);
}

// ---------------- projection GEMM: Y = X @ W^T + bias ----------------
// MODE 0: bf16 out [B,H,S,HD] (Q,K)  MODE 1: bf16 out [B,H,HD,S] (V^T)
// MODE 2: fp32 out [B,S,D] (final)
template<int MODE, bool ABF>
__global__ __launch_bounds__(256) void proj_gemm(
    const void* __restrict__ Aptr, const float* __restrict__ W,
    const float* __restrict__ bias, void* __restrict__ outp)
{
    __shared__ unsigned short Asm[128][72];
    __shared__ unsigned short Bsm[128][72];
    const int tid  = threadIdx.x;
    const int lane = tid & 63, wid = tid >> 6;
    const int l15 = lane & 15, lhi = lane >> 4;
    const int m0 = blockIdx.y * 128, n0 = blockIdx.x * 128;
    const int wr = wid >> 1, wc = wid & 1;

    f32x4 acc[4][4];
#pragma unroll
    for (int i = 0; i < 4; ++i)
#pragma unroll
        for (int j = 0; j < 4; ++j) acc[i][j] = (f32x4)0.f;

    for (int k0 = 0; k0 < 1024; k0 += 64) {
        if constexpr (ABF) {
            const unsigned short* A = (const unsigned short*)Aptr;
#pragma unroll
            for (int p = 0; p < 4; ++p) {
                int idx = p * 256 + tid;
                int row = idx >> 3, c8 = (idx & 7) * 8;
                *reinterpret_cast<int4*>(&Asm[row][c8]) =
                    *reinterpret_cast<const int4*>(&A[(size_t)(m0 + row) * 1024 + k0 + c8]);
            }
        } else {
            const float* A = (const float*)Aptr;
#pragma unroll
            for (int p = 0; p < 8; ++p) {
                int idx = p * 256 + tid;
                int row = idx >> 4, c4 = (idx & 15) * 4;
                float4 v = *reinterpret_cast<const float4*>(&A[(size_t)(m0 + row) * 1024 + k0 + c4]);
                uint2 u;
                u.x = pack2bf(v.x, v.y);
                u.y = pack2bf(v.z, v.w);
                *reinterpret_cast<uint2*>(&Asm[row][c4]) = u;
            }
        }
#pragma unroll
        for (int p = 0; p < 8; ++p) {
            int idx = p * 256 + tid;
            int row = idx >> 4, c4 = (idx & 15) * 4;
            float4 v = *reinterpret_cast<const float4*>(&W[(size_t)(n0 + row) * 1024 + k0 + c4]);
            uint2 u;
            u.x = pack2bf(v.x, v.y);
            u.y = pack2bf(v.z, v.w);
            *reinterpret_cast<uint2*>(&Bsm[row][c4]) = u;
        }
        __syncthreads();
#pragma unroll
        for (int kk = 0; kk < 2; ++kk) {
            const int kc = kk * 32 + 8 * lhi;
            s16x8 af[4], bfv[4];
#pragma unroll
            for (int i = 0; i < 4; ++i)
                af[i] = *reinterpret_cast<const s16x8*>(&Asm[wr * 64 + i * 16 + l15][kc]);
#pragma unroll
            for (int j = 0; j < 4; ++j)
                bfv[j] = *reinterpret_cast<const s16x8*>(&Bsm[wc * 64 + j * 16 + l15][kc]);
#pragma unroll
            for (int i = 0; i < 4; ++i)
#pragma unroll
                for (int j = 0; j < 4; ++j)
                    acc[i][j] = __builtin_amdgcn_mfma_f32_16x16x32_bf16(af[i], bfv[j], acc[i][j], 0, 0, 0);
        }
        __syncthreads();
    }

#pragma unroll
    for (int j = 0; j < 4; ++j) {
        const int col = n0 + wc * 64 + j * 16 + l15;
        const float bv = bias[col];
#pragma unroll
        for (int i = 0; i < 4; ++i) {
#pragma unroll
            for (int r = 0; r < 4; ++r) {
                const int row = m0 + wr * 64 + i * 16 + lhi * 4 + r;
                const float val = acc[i][j][r] + bv;
                if constexpr (MODE == 2) {
                    ((float*)outp)[(size_t)row * 1024 + col] = val;
                } else if constexpr (MODE == 0) {
                    ((unsigned short*)outp)[(size_t)((row >> 11) * 16 + (col >> 6)) * 131072
                                            + (size_t)(row & 2047) * 64 + (col & 63)] = f2bf(val);
                } else {
                    ((unsigned short*)outp)[(size_t)((row >> 11) * 16 + (col >> 6)) * 131072
                                            + (size_t)(col & 63) * 2048 + (row & 2047)] = f2bf(val);
                }
            }
        }
    }
}

// ---------------- flash attention v2 ----------------
// Q,K: [B*H, S, 64] bf16.  Vt: [B*H, 64, S] bf16.  Ao: [B,S,D] bf16.
// grid (S/128, B*H), 256 threads = 4 waves; wave w owns q rows [q0+32w, q0+32w+32).
// Swapped QK^T: mfma(K,Q) -> D[kv][q], lane owns q-row = l15 (per 16-frag f).
__global__ __launch_bounds__(256) void attn_kernel(
    const unsigned short* __restrict__ Q,
    const unsigned short* __restrict__ Kc,
    const unsigned short* __restrict__ Vt,
    unsigned short* __restrict__ Ao)
{
    __shared__ unsigned short Ksm[64][72];
    __shared__ unsigned short Vsm[64][72];       // V^T tile: [d][kv]
    __shared__ unsigned short Psm[4][16][72];    // per-wave P: [q][kv] (f reuses)

    const int tid = threadIdx.x, lane = tid & 63, wid = tid >> 6;
    const int l15 = lane & 15, lhi = lane >> 4;
    const int qt = blockIdx.x, bh = blockIdx.y;
    const size_t base = (size_t)bh * SLEN * 64;
    const unsigned short* Qb = Q + base;
    const unsigned short* Kb = Kc + base;
    const unsigned short* Vb = Vt + base;        // [64][SLEN]
    const int q0 = qt * 128;
    const int qw = q0 + wid * 32;

    // Q fragments (2 row-frags x 2 k-halves) in registers for whole kernel
    s16x8 aq[2][2];
#pragma unroll
    for (int f = 0; f < 2; ++f)
#pragma unroll
        for (int kk = 0; kk < 2; ++kk)
            aq[f][kk] = *reinterpret_cast<const s16x8*>(
                &Qb[(size_t)(qw + 16 * f + l15) * 64 + kk * 32 + 8 * lhi]);

    f32x4 o_acc[2][4];
#pragma unroll
    for (int f = 0; f < 2; ++f)
#pragma unroll
        for (int nb = 0; nb < 4; ++nb) o_acc[f][nb] = (f32x4)0.f;
    float m_r[2] = {-1e30f, -1e30f};
    float l_r[2] = {0.f, 0.f};

    const int nt = 2 * qt + 2;
    const int srow = tid >> 3, sc8 = (tid & 7) * 8;   // staging coords (p adds 32 rows)

    // prolog: stage tile 0
    {
        int4 k0r[2], v0r[2];
#pragma unroll
        for (int p = 0; p < 2; ++p) {
            k0r[p] = *reinterpret_cast<const int4*>(&Kb[(size_t)(srow + p * 32) * 64 + sc8]);
            v0r[p] = *reinterpret_cast<const int4*>(&Vb[(size_t)(srow + p * 32) * SLEN + sc8]);
        }
#pragma unroll
        for (int p = 0; p < 2; ++p) {
            *reinterpret_cast<int4*>(&Ksm[srow + p * 32][sc8]) = k0r[p];
            *reinterpret_cast<int4*>(&Vsm[srow + p * 32][sc8]) = v0r[p];
        }
        __syncthreads();
    }

    int4 kreg[2], vreg[2];
    for (int t = 0; t < nt; ++t) {
        const int kv0 = t * 64;
        const bool pf = (t + 1 < nt);
        if (pf) {   // prefetch next tile into regs (hidden under compute)
            const int nkv = kv0 + 64;
#pragma unroll
            for (int p = 0; p < 2; ++p) {
                kreg[p] = *reinterpret_cast<const int4*>(&Kb[(size_t)(nkv + srow + p * 32) * 64 + sc8]);
                vreg[p] = *reinterpret_cast<const int4*>(&Vb[(size_t)(srow + p * 32) * SLEN + nkv + sc8]);
            }
        }

        if (kv0 <= qw + 31) {   // wave participates (causal)
            const bool diag = (kv0 + 63 > qw);
            // ---- QK^T (swapped): D[kv][q] ----
            f32x4 sc2[2][4];
#pragma unroll
            for (int f = 0; f < 2; ++f)
#pragma unroll
                for (int nb = 0; nb < 4; ++nb) sc2[f][nb] = (f32x4)0.f;
            __builtin_amdgcn_s_setprio(1);
#pragma unroll
            for (int kk = 0; kk < 2; ++kk) {
                const int kc = kk * 32 + 8 * lhi;
                s16x8 ak[4];
#pragma unroll
                for (int nb = 0; nb < 4; ++nb)
                    ak[nb] = *reinterpret_cast<const s16x8*>(&Ksm[nb * 16 + l15][kc]);
#pragma unroll
                for (int f = 0; f < 2; ++f)
#pragma unroll
                    for (int nb = 0; nb < 4; ++nb)
                        sc2[f][nb] = __builtin_amdgcn_mfma_f32_16x16x32_bf16(ak[nb], aq[f][kk], sc2[f][nb], 0, 0, 0);
            }
            __builtin_amdgcn_s_setprio(0);

            // ---- scale + causal mask; lane owns q-row = qw+16f+l15 ----
            float sv[2][4][4], tm[2];
#pragma unroll
            for (int f = 0; f < 2; ++f) {
                float t0 = -1e30f;
#pragma unroll
                for (int nb = 0; nb < 4; ++nb)
#pragma unroll
                    for (int r = 0; r < 4; ++r) {
                        float x = sc2[f][nb][r] * 0.125f;
                        if (diag) {
                            int col = kv0 + nb * 16 + lhi * 4 + r;
                            int row = qw + 16 * f + l15;
                            if (col > row) x = -1e30f;
                        }
                        sv[f][nb][r] = x;
                        t0 = fmaxf(t0, x);
                    }
                t0 = fmaxf(t0, __shfl_xor(t0, 16));
                t0 = fmaxf(t0, __shfl_xor(t0, 32));
                tm[f] = t0;
            }

            // ---- defer-max: rescale only if max grew by > 8 ----
            float alpha[2] = {1.f, 1.f};
            const bool need = __any(fmaxf(tm[0] - m_r[0], tm[1] - m_r[1]) > 8.0f);
            if (need) {
#pragma unroll
                for (int f = 0; f < 2; ++f) {
                    float mn = fmaxf(m_r[f], tm[f]);
                    alpha[f] = __expf(m_r[f] - mn);
                    m_r[f] = mn;
                }
                float ar[2][4];
#pragma unroll
                for (int f = 0; f < 2; ++f)
#pragma unroll
                    for (int r = 0; r < 4; ++r)
                        ar[f][r] = __shfl(alpha[f], lhi * 4 + r);
#pragma unroll
                for (int f = 0; f < 2; ++f)
#pragma unroll
                    for (int nb = 0; nb < 4; ++nb)
#pragma unroll
                        for (int r = 0; r < 4; ++r) o_acc[f][nb][r] *= ar[f][r];
            }

            // ---- exp + sum + P-store + PV per frag f ----
#pragma unroll
            for (int f = 0; f < 2; ++f) {
                float rs = 0.f;
#pragma unroll
                for (int nb = 0; nb < 4; ++nb) {
                    float p0 = __expf(sv[f][nb][0] - m_r[f]);
                    float p1 = __expf(sv[f][nb][1] - m_r[f]);
                    float p2 = __expf(sv[f][nb][2] - m_r[f]);
                    float p3 = __expf(sv[f][nb][3] - m_r[f]);
                    rs += (p0 + p1) + (p2 + p3);
                    uint2 u;
                    u.x = pack2bf(p0, p1);
                    u.y = pack2bf(p2, p3);
                    *reinterpret_cast<uint2*>(&Psm[wid][l15][nb * 16 + lhi * 4]) = u;
                }
                rs += __shfl_xor(rs, 16);
                rs += __shfl_xor(rs, 32);
                l_r[f] = l_r[f] * alpha[f] + rs;

                // PV: O[q][d] += P @ V ; A=P rows q, B=V^T rows d
                __builtin_amdgcn_s_setprio(1);
#pragma unroll
                for (int kk = 0; kk < 2; ++kk) {
                    const int kc = kk * 32 + 8 * lhi;
                    s16x8 pa = *reinterpret_cast<const s16x8*>(&Psm[wid][l15][kc]);
                    s16x8 bvv[4];
#pragma unroll
                    for (int nb = 0; nb < 4; ++nb)
                        bvv[nb] = *reinterpret_cast<const s16x8*>(&Vsm[nb * 16 + l15][kc]);
#pragma unroll
                    for (int nb = 0; nb < 4; ++nb)
                        o_acc[f][nb] = __builtin_amdgcn_mfma_f32_16x16x32_bf16(pa, bvv[nb], o_acc[f][nb], 0, 0, 0);
                }
                __builtin_amdgcn_s_setprio(0);
            }
        }

        __syncthreads();       // all reads of Ksm/Vsm done
        if (pf) {
#pragma unroll
            for (int p = 0; p < 2; ++p) {
                *reinterpret_cast<int4*>(&Ksm[srow + p * 32][sc8]) = kreg[p];
                *reinterpret_cast<int4*>(&Vsm[srow + p * 32][sc8]) = vreg[p];
            }
            __syncthreads();   // staged writes visible for next iter
        }
    }

    // ---- epilogue: out[b, s, h*64+d] = o / l ----
    const int b = bh >> 4, h = bh & 15;
    float linv[2][4];
#pragma unroll
    for (int f = 0; f < 2; ++f)
#pragma unroll
        for (int r = 0; r < 4; ++r)
            linv[f][r] = 1.0f / __shfl(l_r[f], lhi * 4 + r);
#pragma unroll
    for (int f = 0; f < 2; ++f)
#pragma unroll
        for (int nb = 0; nb < 4; ++nb)
#pragma unroll
            for (int r = 0; r < 4; ++r) {
                const int s = qw + 16 * f + lhi * 4 + r;
                Ao[((size_t)b * SLEN + s) * DMOD + h * 64 + nb * 16 + l15] =
                    f2bf(o_acc[f][nb][r] * linv[f][r]);
            }
}

extern "C" void kernel_launch(void* const* d_in, const int* in_sizes, int n_in,
                              void* d_out, int out_size, void* d_ws, size_t ws_size,
                              hipStream_t stream) {
    const float* q  = (const float*)d_in[0];
    const float* k  = (const float*)d_in[1];
    const float* v  = (const float*)d_in[2];
    const float* Wq = (const float*)d_in[4];
    const float* bq = (const float*)d_in[5];
    const float* Wk = (const float*)d_in[6];
    const float* bk = (const float*)d_in[7];
    const float* Wv = (const float*)d_in[8];
    const float* bv = (const float*)d_in[9];
    const float* Wo = (const float*)d_in[10];
    const float* bo = (const float*)d_in[11];

    unsigned short* qb  = (unsigned short*)d_ws;
    unsigned short* kb  = qb + 8388608;
    unsigned short* vtb = kb + 8388608;
    unsigned short* ao  = vtb + 8388608;

    dim3 gg(8, 64), gb(256);
    proj_gemm<0, false><<<gg, gb, 0, stream>>>(q, Wq, bq, qb);
    proj_gemm<0, false><<<gg, gb, 0, stream>>>(k, Wk, bk, kb);
    proj_gemm<1, false><<<gg, gb, 0, stream>>>(v, Wv, bv, vtb);
    attn_kernel<<<dim3(16, 64), gb, 0, stream>>>(qb, kb, vtb, ao);
    proj_gemm<2, true><<<gg, gb, 0, stream>>>(ao, Wo, bo, (float*)d_out);
}

// Round 3
// 349.018 us; speedup vs baseline: 1.2481x; 1.2481x over previous
//
#include <hip/hip_runtime.h>
#include <hip/hip_bf16.h>

// B=4, S=2048, D=1024, H=16, HD=64, causal MHA forward, fp32 in/out.
// bf16 MFMA everywhere. 5 kernels: QKV projections, flash attention, out-proj.

#define SLEN 2048
#define DMOD 1024

typedef __attribute__((ext_vector_type(8))) short s16x8;   // 8 bf16 (4 VGPRs)
typedef __attribute__((ext_vector_type(4))) float f32x4;

__device__ __forceinline__ unsigned short f2bf(float f) {
    union { float f; unsigned u; } v; v.f = f;
    unsigned r = v.u + 0x7fffu + ((v.u >> 16) & 1u);   // RNE
    return (unsigned short)(r >> 16);
}
__device__ __forceinline__ unsigned pack2bf(float a, float b) {
    return (unsigned)f2bf(a) | ((unsigned)f2bf(b) << 16);
}

// ---------------- projection GEMM: Y = X @ W^T + bias ----------------
// MODE 0: bf16 out [B,H,S,HD] (Q,K)  MODE 1: bf16 out [B,H,HD,S] (V^T)
// MODE 2: fp32 out [B,S,D] (final)
template<int MODE, bool ABF>
__global__ __launch_bounds__(256) void proj_gemm(
    const void* __restrict__ Aptr, const float* __restrict__ W,
    const float* __restrict__ bias, void* __restrict__ outp)
{
    __shared__ unsigned short Asm[128][72];
    __shared__ unsigned short Bsm[128][72];
    const int tid  = threadIdx.x;
    const int lane = tid & 63, wid = tid >> 6;
    const int l15 = lane & 15, lhi = lane >> 4;
    const int m0 = blockIdx.y * 128, n0 = blockIdx.x * 128;
    const int wr = wid >> 1, wc = wid & 1;

    f32x4 acc[4][4];
#pragma unroll
    for (int i = 0; i < 4; ++i)
#pragma unroll
        for (int j = 0; j < 4; ++j) acc[i][j] = (f32x4)0.f;

    for (int k0 = 0; k0 < 1024; k0 += 64) {
        if constexpr (ABF) {
            const unsigned short* A = (const unsigned short*)Aptr;
#pragma unroll
            for (int p = 0; p < 4; ++p) {
                int idx = p * 256 + tid;
                int row = idx >> 3, c8 = (idx & 7) * 8;
                *reinterpret_cast<int4*>(&Asm[row][c8]) =
                    *reinterpret_cast<const int4*>(&A[(size_t)(m0 + row) * 1024 + k0 + c8]);
            }
        } else {
            const float* A = (const float*)Aptr;
#pragma unroll
            for (int p = 0; p < 8; ++p) {
                int idx = p * 256 + tid;
                int row = idx >> 4, c4 = (idx & 15) * 4;
                float4 v = *reinterpret_cast<const float4*>(&A[(size_t)(m0 + row) * 1024 + k0 + c4]);
                uint2 u;
                u.x = pack2bf(v.x, v.y);
                u.y = pack2bf(v.z, v.w);
                *reinterpret_cast<uint2*>(&Asm[row][c4]) = u;
            }
        }
#pragma unroll
        for (int p = 0; p < 8; ++p) {
            int idx = p * 256 + tid;
            int row = idx >> 4, c4 = (idx & 15) * 4;
            float4 v = *reinterpret_cast<const float4*>(&W[(size_t)(n0 + row) * 1024 + k0 + c4]);
            uint2 u;
            u.x = pack2bf(v.x, v.y);
            u.y = pack2bf(v.z, v.w);
            *reinterpret_cast<uint2*>(&Bsm[row][c4]) = u;
        }
        __syncthreads();
#pragma unroll
        for (int kk = 0; kk < 2; ++kk) {
            const int kc = kk * 32 + 8 * lhi;
            s16x8 af[4], bfv[4];
#pragma unroll
            for (int i = 0; i < 4; ++i)
                af[i] = *reinterpret_cast<const s16x8*>(&Asm[wr * 64 + i * 16 + l15][kc]);
#pragma unroll
            for (int j = 0; j < 4; ++j)
                bfv[j] = *reinterpret_cast<const s16x8*>(&Bsm[wc * 64 + j * 16 + l15][kc]);
#pragma unroll
            for (int i = 0; i < 4; ++i)
#pragma unroll
                for (int j = 0; j < 4; ++j)
                    acc[i][j] = __builtin_amdgcn_mfma_f32_16x16x32_bf16(af[i], bfv[j], acc[i][j], 0, 0, 0);
        }
        __syncthreads();
    }

#pragma unroll
    for (int j = 0; j < 4; ++j) {
        const int col = n0 + wc * 64 + j * 16 + l15;
        const float bv = bias[col];
#pragma unroll
        for (int i = 0; i < 4; ++i) {
#pragma unroll
            for (int r = 0; r < 4; ++r) {
                const int row = m0 + wr * 64 + i * 16 + lhi * 4 + r;
                const float val = acc[i][j][r] + bv;
                if constexpr (MODE == 2) {
                    ((float*)outp)[(size_t)row * 1024 + col] = val;
                } else if constexpr (MODE == 0) {
                    ((unsigned short*)outp)[(size_t)((row >> 11) * 16 + (col >> 6)) * 131072
                                            + (size_t)(row & 2047) * 64 + (col & 63)] = f2bf(val);
                } else {
                    ((unsigned short*)outp)[(size_t)((row >> 11) * 16 + (col >> 6)) * 131072
                                            + (size_t)(col & 63) * 2048 + (row & 2047)] = f2bf(val);
                }
            }
        }
    }
}

// ---------------- flash attention v3 ----------------
// Q,K: [B*H, S, 64] bf16.  Vt: [B*H, 64, S] bf16.  Ao: [B,S,D] bf16.
// grid (16, B*H), 256 threads = 4 waves. Block bx processes q-tiles {bx, 31-bx}
// (64 rows each) -> uniform 33 kv-tile iterations per block (causal balance).
// Swapped QK^T: mfma(K,Q) -> D[kv][q]; lane owns full q-row = l15 in-register.
#define EXPC 0.18033688011112043f   // 0.125 * log2(e)

__global__ __launch_bounds__(256) void attn_kernel(
    const unsigned short* __restrict__ Q,
    const unsigned short* __restrict__ Kc,
    const unsigned short* __restrict__ Vt,
    unsigned short* __restrict__ Ao)
{
    __shared__ unsigned short Ksm[64][72];
    __shared__ unsigned short Vsm[64][72];       // V^T tile: [d][kv]
    __shared__ unsigned short Psm[4][16][72];    // per-wave P: [q][kv]

    const int tid = threadIdx.x, lane = tid & 63, wid = tid >> 6;
    const int l15 = lane & 15, lhi = lane >> 4;
    const int bx = blockIdx.x, bh = blockIdx.y;
    const size_t base = (size_t)bh * SLEN * 64;
    const unsigned short* Qb = Q + base;
    const unsigned short* Kb = Kc + base;
    const unsigned short* Vb = Vt + base;        // [64][SLEN]
    const int b = bh >> 4, h = bh & 15;
    const int srow = tid >> 3, sc8 = (tid & 7) * 8;

#pragma unroll 1
    for (int seg = 0; seg < 2; ++seg) {
        const int qt = seg ? (31 - bx) : bx;
        const int q0 = qt * 64;
        const int qrow = q0 + wid * 16 + l15;    // this lane's q-row (swapped layout)

        // Q fragments (B-operand: row = q = l15-group, k = lhi*8..)
        s16x8 aq[2];
#pragma unroll
        for (int kk = 0; kk < 2; ++kk)
            aq[kk] = *reinterpret_cast<const s16x8*>(
                &Qb[(size_t)(q0 + wid * 16 + l15) * 64 + kk * 32 + 8 * lhi]);

        f32x4 o_acc[4];
#pragma unroll
        for (int nb = 0; nb < 4; ++nb) o_acc[nb] = (f32x4)0.f;
        float m_r = -1e30f, l_r = 0.f;

        const int nt = qt + 1;

        // prolog: stage tile 0
        {
            int4 kr[2], vr[2];
#pragma unroll
            for (int p = 0; p < 2; ++p) {
                kr[p] = *reinterpret_cast<const int4*>(&Kb[(size_t)(srow + p * 32) * 64 + sc8]);
                vr[p] = *reinterpret_cast<const int4*>(&Vb[(size_t)(srow + p * 32) * SLEN + sc8]);
            }
#pragma unroll
            for (int p = 0; p < 2; ++p) {
                *reinterpret_cast<int4*>(&Ksm[srow + p * 32][sc8]) = kr[p];
                *reinterpret_cast<int4*>(&Vsm[srow + p * 32][sc8]) = vr[p];
            }
            __syncthreads();
        }

        int4 kreg[2], vreg[2];
#pragma unroll 1
        for (int t = 0; t < nt; ++t) {
            const int kv0 = t * 64;
            const bool pf = (t + 1 < nt);
            if (pf) {
                const int nkv = kv0 + 64;
#pragma unroll
                for (int p = 0; p < 2; ++p) {
                    kreg[p] = *reinterpret_cast<const int4*>(&Kb[(size_t)(nkv + srow + p * 32) * 64 + sc8]);
                    vreg[p] = *reinterpret_cast<const int4*>(&Vb[(size_t)(srow + p * 32) * SLEN + nkv + sc8]);
                }
            }

            // ---- QK^T (swapped): D[kv][q] ----
            f32x4 sc2[4];
#pragma unroll
            for (int nb = 0; nb < 4; ++nb) sc2[nb] = (f32x4)0.f;
            __builtin_amdgcn_s_setprio(1);
#pragma unroll
            for (int kk = 0; kk < 2; ++kk) {
                const int kc = kk * 32 + 8 * lhi;
                s16x8 ak[4];
#pragma unroll
                for (int nb = 0; nb < 4; ++nb)
                    ak[nb] = *reinterpret_cast<const s16x8*>(&Ksm[nb * 16 + l15][kc]);
#pragma unroll
                for (int nb = 0; nb < 4; ++nb)
                    sc2[nb] = __builtin_amdgcn_mfma_f32_16x16x32_bf16(ak[nb], aq[kk], sc2[nb], 0, 0, 0);
            }
            __builtin_amdgcn_s_setprio(0);

            // ---- causal mask (diag tiles) + row max (raw scores) ----
            const bool diag = (kv0 + 63 > q0 + wid * 16);
            float tmx = -3e30f;
#pragma unroll
            for (int nb = 0; nb < 4; ++nb)
#pragma unroll
                for (int r = 0; r < 4; ++r) {
                    float x = sc2[nb][r];
                    if (diag && (kv0 + nb * 16 + lhi * 4 + r > qrow)) x = -3e30f;
                    sc2[nb][r] = x;
                    tmx = fmaxf(tmx, x);
                }
            tmx = fmaxf(tmx, __shfl_xor(tmx, 16));
            tmx = fmaxf(tmx, __shfl_xor(tmx, 32));

            // ---- defer-max: rescale only if raw max grew by > 64 (=8 scaled) ----
            if (__any(tmx - m_r > 64.0f)) {
                const float mn = fmaxf(m_r, tmx);
                const float alpha = exp2f((m_r - mn) * EXPC);
                m_r = mn;
                l_r *= alpha;
                float ar[4];
#pragma unroll
                for (int r = 0; r < 4; ++r) ar[r] = __shfl(alpha, lhi * 4 + r);
#pragma unroll
                for (int nb = 0; nb < 4; ++nb)
#pragma unroll
                    for (int r = 0; r < 4; ++r) o_acc[nb][r] *= ar[r];
            }

            // ---- exp2 + sum + packed P-store ----
            float rs = 0.f;
#pragma unroll
            for (int nb = 0; nb < 4; ++nb) {
                float p0 = exp2f((sc2[nb][0] - m_r) * EXPC);
                float p1 = exp2f((sc2[nb][1] - m_r) * EXPC);
                float p2 = exp2f((sc2[nb][2] - m_r) * EXPC);
                float p3 = exp2f((sc2[nb][3] - m_r) * EXPC);
                rs += (p0 + p1) + (p2 + p3);
                uint2 u;
                u.x = pack2bf(p0, p1);
                u.y = pack2bf(p2, p3);
                *reinterpret_cast<uint2*>(&Psm[wid][l15][nb * 16 + lhi * 4]) = u;
            }
            rs += __shfl_xor(rs, 16);
            rs += __shfl_xor(rs, 32);
            l_r += rs;

            // ---- PV: O[q][d] += P @ V  (A=P rows q, B=V^T rows d) ----
            __builtin_amdgcn_s_setprio(1);
#pragma unroll
            for (int kk = 0; kk < 2; ++kk) {
                const int kc = kk * 32 + 8 * lhi;
                s16x8 pa = *reinterpret_cast<const s16x8*>(&Psm[wid][l15][kc]);
                s16x8 bvv[4];
#pragma unroll
                for (int nb = 0; nb < 4; ++nb)
                    bvv[nb] = *reinterpret_cast<const s16x8*>(&Vsm[nb * 16 + l15][kc]);
#pragma unroll
                for (int nb = 0; nb < 4; ++nb)
                    o_acc[nb] = __builtin_amdgcn_mfma_f32_16x16x32_bf16(pa, bvv[nb], o_acc[nb], 0, 0, 0);
            }
            __builtin_amdgcn_s_setprio(0);

            __syncthreads();       // all reads of Ksm/Vsm done
            if (pf) {
#pragma unroll
                for (int p = 0; p < 2; ++p) {
                    *reinterpret_cast<int4*>(&Ksm[srow + p * 32][sc8]) = kreg[p];
                    *reinterpret_cast<int4*>(&Vsm[srow + p * 32][sc8]) = vreg[p];
                }
                __syncthreads();   // staged writes visible
            }
        }

        // ---- epilogue: out[b, s, h*64+d] = o / l ----
        float linv[4];
#pragma unroll
        for (int r = 0; r < 4; ++r)
            linv[r] = 1.0f / __shfl(l_r, lhi * 4 + r);
#pragma unroll
        for (int nb = 0; nb < 4; ++nb)
#pragma unroll
            for (int r = 0; r < 4; ++r) {
                const int s = q0 + wid * 16 + lhi * 4 + r;
                Ao[((size_t)b * SLEN + s) * DMOD + h * 64 + nb * 16 + l15] =
                    f2bf(o_acc[nb][r] * linv[r]);
            }
    }
}

extern "C" void kernel_launch(void* const* d_in, const int* in_sizes, int n_in,
                              void* d_out, int out_size, void* d_ws, size_t ws_size,
                              hipStream_t stream) {
    const float* q  = (const float*)d_in[0];
    const float* k  = (const float*)d_in[1];
    const float* v  = (const float*)d_in[2];
    const float* Wq = (const float*)d_in[4];
    const float* bq = (const float*)d_in[5];
    const float* Wk = (const float*)d_in[6];
    const float* bk = (const float*)d_in[7];
    const float* Wv = (const float*)d_in[8];
    const float* bv = (const float*)d_in[9];
    const float* Wo = (const float*)d_in[10];
    const float* bo = (const float*)d_in[11];

    unsigned short* qb  = (unsigned short*)d_ws;
    unsigned short* kb  = qb + 8388608;
    unsigned short* vtb = kb + 8388608;
    unsigned short* ao  = vtb + 8388608;

    dim3 gg(8, 64), gb(256);
    proj_gemm<0, false><<<gg, gb, 0, stream>>>(q, Wq, bq, qb);
    proj_gemm<0, false><<<gg, gb, 0, stream>>>(k, Wk, bk, kb);
    proj_gemm<1, false><<<gg, gb, 0, stream>>>(v, Wv, bv, vtb);
    attn_kernel<<<dim3(16, 64), gb, 0, stream>>>(qb, kb, vtb, ao);
    proj_gemm<2, true><<<gg, gb, 0, stream>>>(ao, Wo, bo, (float*)d_out);
}

// Round 4
// 338.970 us; speedup vs baseline: 1.2851x; 1.0296x over previous
//
#include <hip/hip_runtime.h>
#include <hip/hip_bf16.h>

// B=4, S=2048, D=1024, H=16, HD=64, causal MHA forward, fp32 in/out.
// bf16 MFMA everywhere. 5 kernels: QKV projections, flash attention, out-proj.

#define SLEN 2048
#define DMOD 1024

typedef __attribute__((ext_vector_type(8))) short s16x8;   // 8 bf16 (4 VGPRs)
typedef __attribute__((ext_vector_type(4))) float f32x4;

__device__ __forceinline__ unsigned short f2bf(float f) {
    union { __hip_bfloat16 h; unsigned short u; } cv;
    cv.h = __float2bfloat16(f);          // native v_cvt (RNE) on gfx950
    return cv.u;
}
__device__ __forceinline__ unsigned pack2bf(float a, float b) {
    return (unsigned)f2bf(a) | ((unsigned)f2bf(b) << 16);
}

// ---------------- projection GEMM: Y = X @ W^T + bias ----------------
// MODE 0: bf16 out [B,H,S,HD] (Q,K)  MODE 1: bf16 out [B,H,HD,S] (V^T)
// MODE 2: fp32 out [B,S,D] (final)
template<int MODE, bool ABF>
__global__ __launch_bounds__(256) void proj_gemm(
    const void* __restrict__ Aptr, const float* __restrict__ W,
    const float* __restrict__ bias, void* __restrict__ outp)
{
    __shared__ unsigned short Asm[128][72];
    __shared__ unsigned short Bsm[128][72];
    const int tid  = threadIdx.x;
    const int lane = tid & 63, wid = tid >> 6;
    const int l15 = lane & 15, lhi = lane >> 4;
    const int m0 = blockIdx.y * 128, n0 = blockIdx.x * 128;
    const int wr = wid >> 1, wc = wid & 1;

    f32x4 acc[4][4];
#pragma unroll
    for (int i = 0; i < 4; ++i)
#pragma unroll
        for (int j = 0; j < 4; ++j) acc[i][j] = (f32x4)0.f;

    for (int k0 = 0; k0 < 1024; k0 += 64) {
        if constexpr (ABF) {
            const unsigned short* A = (const unsigned short*)Aptr;
#pragma unroll
            for (int p = 0; p < 4; ++p) {
                int idx = p * 256 + tid;
                int row = idx >> 3, c8 = (idx & 7) * 8;
                *reinterpret_cast<int4*>(&Asm[row][c8]) =
                    *reinterpret_cast<const int4*>(&A[(size_t)(m0 + row) * 1024 + k0 + c8]);
            }
        } else {
            const float* A = (const float*)Aptr;
#pragma unroll
            for (int p = 0; p < 8; ++p) {
                int idx = p * 256 + tid;
                int row = idx >> 4, c4 = (idx & 15) * 4;
                float4 v = *reinterpret_cast<const float4*>(&A[(size_t)(m0 + row) * 1024 + k0 + c4]);
                uint2 u;
                u.x = pack2bf(v.x, v.y);
                u.y = pack2bf(v.z, v.w);
                *reinterpret_cast<uint2*>(&Asm[row][c4]) = u;
            }
        }
#pragma unroll
        for (int p = 0; p < 8; ++p) {
            int idx = p * 256 + tid;
            int row = idx >> 4, c4 = (idx & 15) * 4;
            float4 v = *reinterpret_cast<const float4*>(&W[(size_t)(n0 + row) * 1024 + k0 + c4]);
            uint2 u;
            u.x = pack2bf(v.x, v.y);
            u.y = pack2bf(v.z, v.w);
            *reinterpret_cast<uint2*>(&Bsm[row][c4]) = u;
        }
        __syncthreads();
#pragma unroll
        for (int kk = 0; kk < 2; ++kk) {
            const int kc = kk * 32 + 8 * lhi;
            s16x8 af[4], bfv[4];
#pragma unroll
            for (int i = 0; i < 4; ++i)
                af[i] = *reinterpret_cast<const s16x8*>(&Asm[wr * 64 + i * 16 + l15][kc]);
#pragma unroll
            for (int j = 0; j < 4; ++j)
                bfv[j] = *reinterpret_cast<const s16x8*>(&Bsm[wc * 64 + j * 16 + l15][kc]);
#pragma unroll
            for (int i = 0; i < 4; ++i)
#pragma unroll
                for (int j = 0; j < 4; ++j)
                    acc[i][j] = __builtin_amdgcn_mfma_f32_16x16x32_bf16(af[i], bfv[j], acc[i][j], 0, 0, 0);
        }
        __syncthreads();
    }

#pragma unroll
    for (int j = 0; j < 4; ++j) {
        const int col = n0 + wc * 64 + j * 16 + l15;
        const float bv = bias[col];
#pragma unroll
        for (int i = 0; i < 4; ++i) {
#pragma unroll
            for (int r = 0; r < 4; ++r) {
                const int row = m0 + wr * 64 + i * 16 + lhi * 4 + r;
                const float val = acc[i][j][r] + bv;
                if constexpr (MODE == 2) {
                    ((float*)outp)[(size_t)row * 1024 + col] = val;
                } else if constexpr (MODE == 0) {
                    ((unsigned short*)outp)[(size_t)((row >> 11) * 16 + (col >> 6)) * 131072
                                            + (size_t)(row & 2047) * 64 + (col & 63)] = f2bf(val);
                } else {
                    ((unsigned short*)outp)[(size_t)((row >> 11) * 16 + (col >> 6)) * 131072
                                            + (size_t)(col & 63) * 2048 + (row & 2047)] = f2bf(val);
                }
            }
        }
    }
}

// ---------------- flash attention v4 ----------------
// Q,K: [B*H, S, 64] bf16.  Vt: [B*H, 64, S] bf16.  Ao: [B,S,D] bf16.
// grid 1024 flat blocks, XCD-swizzled so each XCD owns 8 consecutive bh
// (K/V working set 4MB = one L2). Block processes q-tiles {bx, 31-bx}
// (64 rows each) -> uniform 33 kv-tile iterations (causal balance).
// Swapped QK^T: mfma(K,Q) -> D[kv][q]; lane owns full q-row in-register.
#define EXPC 0.18033688011112043f   // 0.125 * log2(e)

__global__ __launch_bounds__(256, 4) void attn_kernel(
    const unsigned short* __restrict__ Q,
    const unsigned short* __restrict__ Kc,
    const unsigned short* __restrict__ Vt,
    unsigned short* __restrict__ Ao)
{
    __shared__ unsigned short Ksm[64][72];
    __shared__ unsigned short Vsm[64][72];       // V^T tile: [d][kv]
    __shared__ unsigned short Psm[4][16][72];    // per-wave P: [q][kv]

    const int tid = threadIdx.x, lane = tid & 63, wid = tid >> 6;
    const int l15 = lane & 15, lhi = lane >> 4;

    // XCD swizzle: flat%8 = physical XCD; give it 128 consecutive logical
    // blocks = 8 bh (all 16 q-blocks of each). 1024%8==0 -> bijective.
    const int flat = blockIdx.x;
    const int logical = (flat & 7) * 128 + (flat >> 3);
    const int bx = logical & 15, bh = logical >> 4;

    const size_t base = (size_t)bh * SLEN * 64;
    const unsigned short* Qb = Q + base;
    const unsigned short* Kb = Kc + base;
    const unsigned short* Vb = Vt + base;        // [64][SLEN]
    const int b = bh >> 4, h = bh & 15;
    const int srow = tid >> 3, sc8 = (tid & 7) * 8;

#pragma unroll 1
    for (int seg = 0; seg < 2; ++seg) {
        const int qt = seg ? (31 - bx) : bx;
        const int q0 = qt * 64;
        const int qrow = q0 + wid * 16 + l15;    // this lane's q-row

        s16x8 aq[2];
#pragma unroll
        for (int kk = 0; kk < 2; ++kk)
            aq[kk] = *reinterpret_cast<const s16x8*>(
                &Qb[(size_t)(q0 + wid * 16 + l15) * 64 + kk * 32 + 8 * lhi]);

        f32x4 o_acc[4];
#pragma unroll
        for (int nb = 0; nb < 4; ++nb) o_acc[nb] = (f32x4)0.f;
        float m_r = -1e30f, l_r = 0.f;

        const int nt = qt + 1;

        // prolog: stage tile 0
        {
            int4 kr[2], vr[2];
#pragma unroll
            for (int p = 0; p < 2; ++p) {
                kr[p] = *reinterpret_cast<const int4*>(&Kb[(size_t)(srow + p * 32) * 64 + sc8]);
                vr[p] = *reinterpret_cast<const int4*>(&Vb[(size_t)(srow + p * 32) * SLEN + sc8]);
            }
#pragma unroll
            for (int p = 0; p < 2; ++p) {
                *reinterpret_cast<int4*>(&Ksm[srow + p * 32][sc8]) = kr[p];
                *reinterpret_cast<int4*>(&Vsm[srow + p * 32][sc8]) = vr[p];
            }
            __syncthreads();
        }

        int4 kreg[2], vreg[2];
#pragma unroll 1
        for (int t = 0; t < nt; ++t) {
            const int kv0 = t * 64;
            const bool pf = (t + 1 < nt);
            if (pf) {   // prefetch next K/V tile into regs (128-VGPR budget keeps these hoisted)
                const int nkv = kv0 + 64;
#pragma unroll
                for (int p = 0; p < 2; ++p) {
                    kreg[p] = *reinterpret_cast<const int4*>(&Kb[(size_t)(nkv + srow + p * 32) * 64 + sc8]);
                    vreg[p] = *reinterpret_cast<const int4*>(&Vb[(size_t)(srow + p * 32) * SLEN + nkv + sc8]);
                }
            }

            // ---- QK^T (swapped): D[kv][q] ----
            f32x4 sc2[4];
#pragma unroll
            for (int nb = 0; nb < 4; ++nb) sc2[nb] = (f32x4)0.f;
            __builtin_amdgcn_s_setprio(1);
#pragma unroll
            for (int kk = 0; kk < 2; ++kk) {
                const int kc = kk * 32 + 8 * lhi;
                s16x8 ak[4];
#pragma unroll
                for (int nb = 0; nb < 4; ++nb)
                    ak[nb] = *reinterpret_cast<const s16x8*>(&Ksm[nb * 16 + l15][kc]);
#pragma unroll
                for (int nb = 0; nb < 4; ++nb)
                    sc2[nb] = __builtin_amdgcn_mfma_f32_16x16x32_bf16(ak[nb], aq[kk], sc2[nb], 0, 0, 0);
            }
            __builtin_amdgcn_s_setprio(0);

            // ---- causal mask (diag tiles) + row max (raw scores) ----
            const bool diag = (kv0 + 63 > q0 + wid * 16);
            float tmx = -3e30f;
#pragma unroll
            for (int nb = 0; nb < 4; ++nb)
#pragma unroll
                for (int r = 0; r < 4; ++r) {
                    float x = sc2[nb][r];
                    if (diag && (kv0 + nb * 16 + lhi * 4 + r > qrow)) x = -3e30f;
                    sc2[nb][r] = x;
                    tmx = fmaxf(tmx, x);
                }
            tmx = fmaxf(tmx, __shfl_xor(tmx, 16));
            tmx = fmaxf(tmx, __shfl_xor(tmx, 32));

            // ---- defer-max: rescale only if raw max grew by > 64 (=8 scaled) ----
            if (__any(tmx - m_r > 64.0f)) {
                const float mn = fmaxf(m_r, tmx);
                const float alpha = exp2f((m_r - mn) * EXPC);
                m_r = mn;
                l_r *= alpha;
                float ar[4];
#pragma unroll
                for (int r = 0; r < 4; ++r) ar[r] = __shfl(alpha, lhi * 4 + r);
#pragma unroll
                for (int nb = 0; nb < 4; ++nb)
#pragma unroll
                    for (int r = 0; r < 4; ++r) o_acc[nb][r] *= ar[r];
            }

            // ---- exp2 (fma-folded) + packed P-store ----
            const float negmC = -m_r * EXPC;
            float s4[4];
#pragma unroll
            for (int nb = 0; nb < 4; ++nb) {
                float p0 = exp2f(fmaf(sc2[nb][0], EXPC, negmC));
                float p1 = exp2f(fmaf(sc2[nb][1], EXPC, negmC));
                float p2 = exp2f(fmaf(sc2[nb][2], EXPC, negmC));
                float p3 = exp2f(fmaf(sc2[nb][3], EXPC, negmC));
                s4[nb] = (p0 + p1) + (p2 + p3);
                uint2 u;
                u.x = pack2bf(p0, p1);
                u.y = pack2bf(p2, p3);
                *reinterpret_cast<uint2*>(&Psm[wid][l15][nb * 16 + lhi * 4]) = u;
            }

            // ---- PV: O[q][d] += P @ V  (A=P rows q, B=V^T rows d) ----
            __builtin_amdgcn_s_setprio(1);
#pragma unroll
            for (int kk = 0; kk < 2; ++kk) {
                const int kc = kk * 32 + 8 * lhi;
                s16x8 pa = *reinterpret_cast<const s16x8*>(&Psm[wid][l15][kc]);
                s16x8 bvv[4];
#pragma unroll
                for (int nb = 0; nb < 4; ++nb)
                    bvv[nb] = *reinterpret_cast<const s16x8*>(&Vsm[nb * 16 + l15][kc]);
#pragma unroll
                for (int nb = 0; nb < 4; ++nb)
                    o_acc[nb] = __builtin_amdgcn_mfma_f32_16x16x32_bf16(pa, bvv[nb], o_acc[nb], 0, 0, 0);
            }
            __builtin_amdgcn_s_setprio(0);

            // ---- l update (off the PV critical path) ----
            float rs = (s4[0] + s4[1]) + (s4[2] + s4[3]);
            rs += __shfl_xor(rs, 16);
            rs += __shfl_xor(rs, 32);
            l_r += rs;

            __syncthreads();       // all reads of Ksm/Vsm done
            if (pf) {
#pragma unroll
                for (int p = 0; p < 2; ++p) {
                    *reinterpret_cast<int4*>(&Ksm[srow + p * 32][sc8]) = kreg[p];
                    *reinterpret_cast<int4*>(&Vsm[srow + p * 32][sc8]) = vreg[p];
                }
                __syncthreads();   // staged writes visible
            }
        }

        // ---- epilogue: out[b, s, h*64+d] = o / l ----
        float linv[4];
#pragma unroll
        for (int r = 0; r < 4; ++r)
            linv[r] = 1.0f / __shfl(l_r, lhi * 4 + r);
#pragma unroll
        for (int nb = 0; nb < 4; ++nb)
#pragma unroll
            for (int r = 0; r < 4; ++r) {
                const int s = q0 + wid * 16 + lhi * 4 + r;
                Ao[((size_t)b * SLEN + s) * DMOD + h * 64 + nb * 16 + l15] =
                    f2bf(o_acc[nb][r] * linv[r]);
            }
    }
}

extern "C" void kernel_launch(void* const* d_in, const int* in_sizes, int n_in,
                              void* d_out, int out_size, void* d_ws, size_t ws_size,
                              hipStream_t stream) {
    const float* q  = (const float*)d_in[0];
    const float* k  = (const float*)d_in[1];
    const float* v  = (const float*)d_in[2];
    const float* Wq = (const float*)d_in[4];
    const float* bq = (const float*)d_in[5];
    const float* Wk = (const float*)d_in[6];
    const float* bk = (const float*)d_in[7];
    const float* Wv = (const float*)d_in[8];
    const float* bv = (const float*)d_in[9];
    const float* Wo = (const float*)d_in[10];
    const float* bo = (const float*)d_in[11];

    unsigned short* qb  = (unsigned short*)d_ws;
    unsigned short* kb  = qb + 8388608;
    unsigned short* vtb = kb + 8388608;
    unsigned short* ao  = vtb + 8388608;

    dim3 gg(8, 64), gb(256);
    proj_gemm<0, false><<<gg, gb, 0, stream>>>(q, Wq, bq, qb);
    proj_gemm<0, false><<<gg, gb, 0, stream>>>(k, Wk, bk, kb);
    proj_gemm<1, false><<<gg, gb, 0, stream>>>(v, Wv, bv, vtb);
    attn_kernel<<<dim3(1024), gb, 0, stream>>>(qb, kb, vtb, ao);
    proj_gemm<2, true><<<gg, gb, 0, stream>>>(ao, Wo, bo, (float*)d_out);
}

// Round 5
// 267.962 us; speedup vs baseline: 1.6256x; 1.2650x over previous
//
#include <hip/hip_runtime.h>
#include <hip/hip_bf16.h>

// B=4, S=2048, D=1024, H=16, HD=64, causal MHA forward, fp32 in/out.
// bf16 MFMA everywhere. 5 kernels: QKV projections, flash attention, out-proj.

#define SLEN 2048
#define DMOD 1024

typedef __attribute__((ext_vector_type(8))) short s16x8;   // 8 bf16 (4 VGPRs)
typedef __attribute__((ext_vector_type(4))) float f32x4;

__device__ __forceinline__ unsigned short f2bf(float f) {
    union { __hip_bfloat16 h; unsigned short u; } cv;
    cv.h = __float2bfloat16(f);          // native cvt (RNE)
    return cv.u;
}
__device__ __forceinline__ unsigned pack2bf(float a, float b) {
    return (unsigned)f2bf(a) | ((unsigned)f2bf(b) << 16);
}

// async global->LDS, 16B per lane; LDS dest is wave-uniform base + lane*16
__device__ __forceinline__ void gload_lds16(const void* g, void* l) {
    __builtin_amdgcn_global_load_lds(
        (const __attribute__((address_space(1))) void*)g,
        (__attribute__((address_space(3))) void*)l, 16, 0, 0);
}

// ---------------- projection GEMM: Y = X @ W^T + bias ----------------
// MODE 0: bf16 out [B,H,S,HD] (Q,K)  MODE 1: bf16 out [B,H,HD,S] (V^T)
// MODE 2: fp32 out [B,S,D] (final)
template<int MODE, bool ABF>
__global__ __launch_bounds__(256) void proj_gemm(
    const void* __restrict__ Aptr, const float* __restrict__ W,
    const float* __restrict__ bias, void* __restrict__ outp)
{
    __shared__ unsigned short Asm[128][72];
    __shared__ unsigned short Bsm[128][72];
    const int tid  = threadIdx.x;
    const int lane = tid & 63, wid = tid >> 6;
    const int l15 = lane & 15, lhi = lane >> 4;
    const int m0 = blockIdx.y * 128, n0 = blockIdx.x * 128;
    const int wr = wid >> 1, wc = wid & 1;

    f32x4 acc[4][4];
#pragma unroll
    for (int i = 0; i < 4; ++i)
#pragma unroll
        for (int j = 0; j < 4; ++j) acc[i][j] = (f32x4)0.f;

    for (int k0 = 0; k0 < 1024; k0 += 64) {
        if constexpr (ABF) {
            const unsigned short* A = (const unsigned short*)Aptr;
#pragma unroll
            for (int p = 0; p < 4; ++p) {
                int idx = p * 256 + tid;
                int row = idx >> 3, c8 = (idx & 7) * 8;
                *reinterpret_cast<int4*>(&Asm[row][c8]) =
                    *reinterpret_cast<const int4*>(&A[(size_t)(m0 + row) * 1024 + k0 + c8]);
            }
        } else {
            const float* A = (const float*)Aptr;
#pragma unroll
            for (int p = 0; p < 8; ++p) {
                int idx = p * 256 + tid;
                int row = idx >> 4, c4 = (idx & 15) * 4;
                float4 v = *reinterpret_cast<const float4*>(&A[(size_t)(m0 + row) * 1024 + k0 + c4]);
                uint2 u;
                u.x = pack2bf(v.x, v.y);
                u.y = pack2bf(v.z, v.w);
                *reinterpret_cast<uint2*>(&Asm[row][c4]) = u;
            }
        }
#pragma unroll
        for (int p = 0; p < 8; ++p) {
            int idx = p * 256 + tid;
            int row = idx >> 4, c4 = (idx & 15) * 4;
            float4 v = *reinterpret_cast<const float4*>(&W[(size_t)(n0 + row) * 1024 + k0 + c4]);
            uint2 u;
            u.x = pack2bf(v.x, v.y);
            u.y = pack2bf(v.z, v.w);
            *reinterpret_cast<uint2*>(&Bsm[row][c4]) = u;
        }
        __syncthreads();
#pragma unroll
        for (int kk = 0; kk < 2; ++kk) {
            const int kc = kk * 32 + 8 * lhi;
            s16x8 af[4], bfv[4];
#pragma unroll
            for (int i = 0; i < 4; ++i)
                af[i] = *reinterpret_cast<const s16x8*>(&Asm[wr * 64 + i * 16 + l15][kc]);
#pragma unroll
            for (int j = 0; j < 4; ++j)
                bfv[j] = *reinterpret_cast<const s16x8*>(&Bsm[wc * 64 + j * 16 + l15][kc]);
#pragma unroll
            for (int i = 0; i < 4; ++i)
#pragma unroll
                for (int j = 0; j < 4; ++j)
                    acc[i][j] = __builtin_amdgcn_mfma_f32_16x16x32_bf16(af[i], bfv[j], acc[i][j], 0, 0, 0);
        }
        __syncthreads();
    }

#pragma unroll
    for (int j = 0; j < 4; ++j) {
        const int col = n0 + wc * 64 + j * 16 + l15;
        const float bv = bias[col];
#pragma unroll
        for (int i = 0; i < 4; ++i) {
#pragma unroll
            for (int r = 0; r < 4; ++r) {
                const int row = m0 + wr * 64 + i * 16 + lhi * 4 + r;
                const float val = acc[i][j][r] + bv;
                if constexpr (MODE == 2) {
                    ((float*)outp)[(size_t)row * 1024 + col] = val;
                } else if constexpr (MODE == 0) {
                    ((unsigned short*)outp)[(size_t)((row >> 11) * 16 + (col >> 6)) * 131072
                                            + (size_t)(row & 2047) * 64 + (col & 63)] = f2bf(val);
                } else {
                    ((unsigned short*)outp)[(size_t)((row >> 11) * 16 + (col >> 6)) * 131072
                                            + (size_t)(col & 63) * 2048 + (row & 2047)] = f2bf(val);
                }
            }
        }
    }
}

// ---------------- flash attention v5 ----------------
// Q,K: [B*H, S, 64] bf16.  Vt: [B*H, 64, S] bf16.  Ao: [B,S,D] bf16.
// grid 1024 flat, XCD-swizzled (each XCD owns 8 bh). Block bx does q-tiles
// {bx, 31-bx} (64 rows each): 33 kv-iterations uniform.
// K/V staged via async global_load_lds into double-buffered UNPADDED [64][64]
// tiles, XOR-swizzled (granule: col16 ^= row&7) via pre-swizzled global src.
// One barrier per kv-iteration. Swapped QK^T; per-lane partial l; max-reduce
// only inside the rare rescale branch.
#define EXPC 0.18033688011112043f   // 0.125 * log2(e)

__global__ __launch_bounds__(256, 4) void attn_kernel(
    const unsigned short* __restrict__ Q,
    const unsigned short* __restrict__ Kc,
    const unsigned short* __restrict__ Vt,
    unsigned short* __restrict__ Ao)
{
    __shared__ unsigned short Kbuf[2][4096];   // [64 kv][64 d] swizzled, 8KB each
    __shared__ unsigned short Vbuf[2][4096];   // [64 d][64 kv] swizzled
    __shared__ unsigned short Psm[4][1024];    // per-wave [16 q][64 kv] swizzled

    const int tid = threadIdx.x, lane = tid & 63, wid = tid >> 6;
    const int l15 = lane & 15, lhi = lane >> 4;
    const int sK = l15 & 7;                    // read-side swizzle key
    const int sub = lane >> 3, c8s = lane & 7; // staging coords

    // XCD swizzle: 1024 blocks, flat%8 = XCD, each XCD gets 8 consecutive bh.
    const int flat = blockIdx.x;
    const int logical = (flat & 7) * 128 + (flat >> 3);
    const int bx = logical & 15, bh = logical >> 4;

    const size_t base = (size_t)bh * SLEN * 64;
    const unsigned short* Qb = Q + base;
    const unsigned short* Kb = Kc + base;
    const unsigned short* Vb = Vt + base;      // [64][SLEN]
    const int b = bh >> 4, h = bh & 15;

#pragma unroll 1
    for (int seg = 0; seg < 2; ++seg) {
        const int qt = seg ? (31 - bx) : bx;
        const int q0 = qt * 64;
        const int qrow = q0 + wid * 16 + l15;

        s16x8 aq[2];
#pragma unroll
        for (int kk = 0; kk < 2; ++kk)
            aq[kk] = *reinterpret_cast<const s16x8*>(
                &Qb[(size_t)(q0 + wid * 16 + l15) * 64 + kk * 32 + 8 * lhi]);

        f32x4 o_acc[4];
#pragma unroll
        for (int nb = 0; nb < 4; ++nb) o_acc[nb] = (f32x4)0.f;
        float m_r = -1e30f, l_part = 0.f;

        const int nt = qt + 1;

        // ---- stage tile kv-tile `tt` into buffer bsel (async DMA) ----
        // wave wid stages rows [16*wid, 16*wid+16): 2 instrs x (8 rows, 1KB)
        auto stage = [&](int tt, int bsel) {
#pragma unroll
            for (int i = 0; i < 2; ++i) {
                const int row = 16 * wid + 8 * i + sub;
                const int col16 = c8s ^ (row & 7);          // pre-swizzled src
                gload_lds16(&Kb[(size_t)(tt * 64 + row) * 64 + col16 * 8],
                            (char*)&Kbuf[bsel][0] + wid * 2048 + i * 1024);
                gload_lds16(&Vb[(size_t)row * SLEN + tt * 64 + col16 * 8],
                            (char*)&Vbuf[bsel][0] + wid * 2048 + i * 1024);
            }
        };

        stage(0, 0);
        __syncthreads();   // drains vmcnt before barrier (compiler-emitted)

        int cur = 0;
#pragma unroll 1
        for (int t = 0; t < nt; ++t) {
            const int kv0 = t * 64;
            if (t + 1 < nt) stage(t + 1, cur ^ 1);   // async, overlaps compute

            const unsigned short* KL = Kbuf[cur];
            const unsigned short* VL = Vbuf[cur];

            // ---- QK^T (swapped): D[kv][q], kv = nb*16+lhi*4+r, q = l15 ----
            f32x4 sc2[4];
#pragma unroll
            for (int nb = 0; nb < 4; ++nb) sc2[nb] = (f32x4)0.f;
            __builtin_amdgcn_s_setprio(1);
#pragma unroll
            for (int kk = 0; kk < 2; ++kk) {
                s16x8 ak[4];
#pragma unroll
                for (int nb = 0; nb < 4; ++nb) {
                    const int g = (nb * 16 + l15) * 8 + ((4 * kk + lhi) ^ sK);
                    ak[nb] = *reinterpret_cast<const s16x8*>(&KL[g * 8]);
                }
#pragma unroll
                for (int nb = 0; nb < 4; ++nb)
                    sc2[nb] = __builtin_amdgcn_mfma_f32_16x16x32_bf16(ak[nb], aq[kk], sc2[nb], 0, 0, 0);
            }
            __builtin_amdgcn_s_setprio(0);

            // ---- causal mask + in-lane partial max (no cross-lane) ----
            const bool diag = (kv0 + 63 > q0 + wid * 16);
            float tmx = -3e30f;
#pragma unroll
            for (int nb = 0; nb < 4; ++nb)
#pragma unroll
                for (int r = 0; r < 4; ++r) {
                    float x = sc2[nb][r];
                    if (diag && (kv0 + nb * 16 + lhi * 4 + r > qrow)) x = -3e30f;
                    sc2[nb][r] = x;
                    tmx = fmaxf(tmx, x);
                }

            // ---- rescale branch (rare): full row max via 2 shfls ----
            if (__any(tmx - m_r > 64.0f)) {
                float tf = fmaxf(tmx, __shfl_xor(tmx, 16));
                tf = fmaxf(tf, __shfl_xor(tf, 32));
                const float mn = fmaxf(m_r, tf);
                const float alpha = exp2f((m_r - mn) * EXPC);
                m_r = mn;
                l_part *= alpha;
                float ar[4];
#pragma unroll
                for (int r = 0; r < 4; ++r) ar[r] = __shfl(alpha, lhi * 4 + r);
#pragma unroll
                for (int nb = 0; nb < 4; ++nb)
#pragma unroll
                    for (int r = 0; r < 4; ++r) o_acc[nb][r] *= ar[r];
            }

            // ---- exp2 + swizzled packed P-store + per-lane partial sum ----
            const float negmC = -m_r * EXPC;
            unsigned short* Pw = &Psm[wid][0];
#pragma unroll
            for (int nb = 0; nb < 4; ++nb) {
                float p0 = exp2f(fmaf(sc2[nb][0], EXPC, negmC));
                float p1 = exp2f(fmaf(sc2[nb][1], EXPC, negmC));
                float p2 = exp2f(fmaf(sc2[nb][2], EXPC, negmC));
                float p3 = exp2f(fmaf(sc2[nb][3], EXPC, negmC));
                l_part += (p0 + p1) + (p2 + p3);
                uint2 u;
                u.x = pack2bf(p0, p1);
                u.y = pack2bf(p2, p3);
                const int g8 = l15 * 16 + ((nb * 4 + lhi) ^ (2 * sK));
                *reinterpret_cast<uint2*>(&Pw[g8 * 4]) = u;
            }

            // ---- PV: O[q][d] += P @ V ----
            __builtin_amdgcn_s_setprio(1);
#pragma unroll
            for (int kk = 0; kk < 2; ++kk) {
                const int gp = l15 * 8 + ((4 * kk + lhi) ^ sK);
                s16x8 pa = *reinterpret_cast<const s16x8*>(&Pw[gp * 8]);
                s16x8 bvv[4];
#pragma unroll
                for (int nb = 0; nb < 4; ++nb) {
                    const int g = (nb * 16 + l15) * 8 + ((4 * kk + lhi) ^ sK);
                    bvv[nb] = *reinterpret_cast<const s16x8*>(&VL[g * 8]);
                }
#pragma unroll
                for (int nb = 0; nb < 4; ++nb)
                    o_acc[nb] = __builtin_amdgcn_mfma_f32_16x16x32_bf16(pa, bvv[nb], o_acc[nb], 0, 0, 0);
            }
            __builtin_amdgcn_s_setprio(0);

            __syncthreads();   // drains DMA (vmcnt) + LDS; flips buffer safely
            cur ^= 1;
        }

        // ---- epilogue: reduce l once, then out[b,s,h*64+d] = o/l ----
        float lf = l_part + __shfl_xor(l_part, 16);
        lf += __shfl_xor(lf, 32);
        float linv[4];
#pragma unroll
        for (int r = 0; r < 4; ++r)
            linv[r] = 1.0f / __shfl(lf, lhi * 4 + r);
#pragma unroll
        for (int nb = 0; nb < 4; ++nb)
#pragma unroll
            for (int r = 0; r < 4; ++r) {
                const int s = q0 + wid * 16 + lhi * 4 + r;
                Ao[((size_t)b * SLEN + s) * DMOD + h * 64 + nb * 16 + l15] =
                    f2bf(o_acc[nb][r] * linv[r]);
            }
        if (seg == 0) __syncthreads();   // protect buffers before re-stage
    }
}

extern "C" void kernel_launch(void* const* d_in, const int* in_sizes, int n_in,
                              void* d_out, int out_size, void* d_ws, size_t ws_size,
                              hipStream_t stream) {
    const float* q  = (const float*)d_in[0];
    const float* k  = (const float*)d_in[1];
    const float* v  = (const float*)d_in[2];
    const float* Wq = (const float*)d_in[4];
    const float* bq = (const float*)d_in[5];
    const float* Wk = (const float*)d_in[6];
    const float* bk = (const float*)d_in[7];
    const float* Wv = (const float*)d_in[8];
    const float* bv = (const float*)d_in[9];
    const float* Wo = (const float*)d_in[10];
    const float* bo = (const float*)d_in[11];

    unsigned short* qb  = (unsigned short*)d_ws;
    unsigned short* kb  = qb + 8388608;
    unsigned short* vtb = kb + 8388608;
    unsigned short* ao  = vtb + 8388608;

    dim3 gg(8, 64), gb(256);
    proj_gemm<0, false><<<gg, gb, 0, stream>>>(q, Wq, bq, qb);
    proj_gemm<0, false><<<gg, gb, 0, stream>>>(k, Wk, bk, kb);
    proj_gemm<1, false><<<gg, gb, 0, stream>>>(v, Wv, bv, vtb);
    attn_kernel<<<dim3(1024), gb, 0, stream>>>(qb, kb, vtb, ao);
    proj_gemm<2, true><<<gg, gb, 0, stream>>>(ao, Wo, bo, (float*)d_out);
}

// Round 6
// 206.535 us; speedup vs baseline: 2.1091x; 1.2974x over previous
//
#include <hip/hip_runtime.h>
#include <hip/hip_bf16.h>

// B=4, S=2048, D=1024, H=16, HD=64, causal MHA forward, fp32 in/out.
// Pipeline: convert(fp32->bf16) -> 3 proj GEMMs -> flash attn -> out GEMM.

#define SLEN 2048
#define DMOD 1024

typedef __attribute__((ext_vector_type(8))) short s16x8;   // 8 bf16 (4 VGPRs)
typedef __attribute__((ext_vector_type(4))) float f32x4;

__device__ __forceinline__ unsigned short f2bf(float f) {
    union { __hip_bfloat16 h; unsigned short u; } cv;
    cv.h = __float2bfloat16(f);          // native cvt (RNE)
    return cv.u;
}
__device__ __forceinline__ unsigned pack2bf(float a, float b) {
    return (unsigned)f2bf(a) | ((unsigned)f2bf(b) << 16);
}

// async global->LDS, 16B per lane; LDS dest is wave-uniform base + lane*16
__device__ __forceinline__ void gload_lds16(const void* g, void* l) {
    __builtin_amdgcn_global_load_lds(
        (const __attribute__((address_space(1))) void*)g,
        (__attribute__((address_space(3))) void*)l, 16, 0, 0);
}

// ---------------- fp32 -> bf16 convert ----------------
// blocks 0..3071: q/k/v (1024 blocks each, 8.39M el); 3072..3583: Wq/Wk/Wv/Wo
// (128 blocks each, 1.05M el). Each block converts 8192 elements.
__global__ __launch_bounds__(256) void convert_bf16(
    const float* __restrict__ q, const float* __restrict__ k,
    const float* __restrict__ v, const float* __restrict__ wq,
    const float* __restrict__ wk, const float* __restrict__ wv,
    const float* __restrict__ wo, unsigned short* __restrict__ ws)
{
    const int bid = blockIdx.x, tid = threadIdx.x;
    const float* src;
    unsigned short* dst;
    size_t off;
    if (bid < 3072) {
        const int t = bid >> 10;
        src = (t == 0) ? q : (t == 1) ? k : v;
        dst = ws + (size_t)t * 8388608;
        off = (size_t)(bid & 1023) * 8192;
    } else {
        const int w = (bid - 3072) >> 7;
        src = (w == 0) ? wq : (w == 1) ? wk : (w == 2) ? wv : wo;
        dst = ws + 25165824 + (size_t)w * 1048576;
        off = (size_t)((bid - 3072) & 127) * 8192;
    }
#pragma unroll
    for (int i = 0; i < 8; ++i) {
        const size_t e = off + (size_t)(i * 256 + tid) * 4;
        float4 x = *reinterpret_cast<const float4*>(&src[e]);
        uint2 u;
        u.x = pack2bf(x.x, x.y);
        u.y = pack2bf(x.z, x.w);
        *reinterpret_cast<uint2*>(&dst[e]) = u;
    }
}

// ---------------- bf16 GEMM: Y = A @ W^T + bias ----------------
// A: [8192,1024] bf16, W: [1024,1024] bf16 ([e][d] = B^T form), bias fp32.
// 128x128 tile, BK=64, 4 waves. Both operands staged via global_load_lds
// (linear LDS dest) with XOR-swizzled global source; ds_read uses same XOR
// -> 2-way bank conflicts (free). m97 2-barrier structure.
// MODE 0: bf16 out [B,H,S,HD] (Q,K)  MODE 1: bf16 out [B,H,HD,S] (V^T)
// MODE 2: fp32 out [B,S,D] (final)
template<int MODE>
__global__ __launch_bounds__(256) void gemm_bf16(
    const unsigned short* __restrict__ A, const unsigned short* __restrict__ W,
    const float* __restrict__ bias, void* __restrict__ outp)
{
    __shared__ unsigned short Asm[128 * 64];   // [row][8 granules of 8 el], swizzled
    __shared__ unsigned short Bsm[128 * 64];

    const int tid  = threadIdx.x;
    const int lane = tid & 63, wid = tid >> 6;
    const int l15 = lane & 15, lhi = lane >> 4;

    // XCD swizzle: 512 blocks, each XCD gets 8 consecutive m-panels (all n).
    const int flat = blockIdx.x;
    const int logical = (flat & 7) * 64 + (flat >> 3);
    const int m0 = (logical >> 3) * 128, n0 = (logical & 7) * 128;

    const int wr = wid >> 1, wc = wid & 1;
    // staging coords: lane>>3 = row-within-8, lane&7 = granule; key = lane>>3
    const int srow = lane >> 3;
    const int sgr  = (lane & 7) ^ srow;

    f32x4 acc[4][4];
#pragma unroll
    for (int i = 0; i < 4; ++i)
#pragma unroll
        for (int j = 0; j < 4; ++j) acc[i][j] = (f32x4)0.f;

#pragma unroll 1
    for (int k0 = 0; k0 < 1024; k0 += 64) {
        // stage A,B tiles (128x64 each) via async DMA, swizzled source
#pragma unroll
        for (int i = 0; i < 4; ++i) {
            const int rl = i * 32 + wid * 8 + srow;
            gload_lds16(&A[(size_t)(m0 + rl) * 1024 + k0 + sgr * 8],
                        (char*)Asm + i * 4096 + wid * 1024);
            gload_lds16(&W[(size_t)(n0 + rl) * 1024 + k0 + sgr * 8],
                        (char*)Bsm + i * 4096 + wid * 1024);
        }
        __syncthreads();   // drains vmcnt (compiler-emitted before barrier)

#pragma unroll
        for (int kk = 0; kk < 2; ++kk) {
            s16x8 af[4], bfv[4];
#pragma unroll
            for (int i = 0; i < 4; ++i) {
                const int row = wr * 64 + i * 16 + l15;
                const int s = (4 * kk + lhi) ^ (l15 & 7);
                af[i] = *reinterpret_cast<const s16x8*>(&Asm[row * 64 + s * 8]);
            }
#pragma unroll
            for (int j = 0; j < 4; ++j) {
                const int row = wc * 64 + j * 16 + l15;
                const int s = (4 * kk + lhi) ^ (l15 & 7);
                bfv[j] = *reinterpret_cast<const s16x8*>(&Bsm[row * 64 + s * 8]);
            }
#pragma unroll
            for (int i = 0; i < 4; ++i)
#pragma unroll
                for (int j = 0; j < 4; ++j)
                    acc[i][j] = __builtin_amdgcn_mfma_f32_16x16x32_bf16(af[i], bfv[j], acc[i][j], 0, 0, 0);
        }
        __syncthreads();   // reads done before next stage overwrites
    }

    // epilogue: C/D layout col=lane&15, row=(lane>>4)*4+reg
#pragma unroll
    for (int j = 0; j < 4; ++j) {
        const int col = n0 + wc * 64 + j * 16 + l15;
        const float bv = bias[col];
#pragma unroll
        for (int i = 0; i < 4; ++i) {
#pragma unroll
            for (int r = 0; r < 4; ++r) {
                const int row = m0 + wr * 64 + i * 16 + lhi * 4 + r;
                const float val = acc[i][j][r] + bv;
                if constexpr (MODE == 2) {
                    ((float*)outp)[(size_t)row * 1024 + col] = val;
                } else if constexpr (MODE == 0) {
                    ((unsigned short*)outp)[(size_t)((row >> 11) * 16 + (col >> 6)) * 131072
                                            + (size_t)(row & 2047) * 64 + (col & 63)] = f2bf(val);
                } else {
                    ((unsigned short*)outp)[(size_t)((row >> 11) * 16 + (col >> 6)) * 131072
                                            + (size_t)(col & 63) * 2048 + (row & 2047)] = f2bf(val);
                }
            }
        }
    }
}

// ---------------- flash attention v5 (unchanged from round 5) ----------------
#define EXPC 0.18033688011112043f   // 0.125 * log2(e)

__global__ __launch_bounds__(256, 4) void attn_kernel(
    const unsigned short* __restrict__ Q,
    const unsigned short* __restrict__ Kc,
    const unsigned short* __restrict__ Vt,
    unsigned short* __restrict__ Ao)
{
    __shared__ unsigned short Kbuf[2][4096];
    __shared__ unsigned short Vbuf[2][4096];
    __shared__ unsigned short Psm[4][1024];

    const int tid = threadIdx.x, lane = tid & 63, wid = tid >> 6;
    const int l15 = lane & 15, lhi = lane >> 4;
    const int sK = l15 & 7;
    const int sub = lane >> 3, c8s = lane & 7;

    const int flat = blockIdx.x;
    const int logical = (flat & 7) * 128 + (flat >> 3);
    const int bx = logical & 15, bh = logical >> 4;

    const size_t base = (size_t)bh * SLEN * 64;
    const unsigned short* Qb = Q + base;
    const unsigned short* Kb = Kc + base;
    const unsigned short* Vb = Vt + base;
    const int b = bh >> 4, h = bh & 15;

#pragma unroll 1
    for (int seg = 0; seg < 2; ++seg) {
        const int qt = seg ? (31 - bx) : bx;
        const int q0 = qt * 64;
        const int qrow = q0 + wid * 16 + l15;

        s16x8 aq[2];
#pragma unroll
        for (int kk = 0; kk < 2; ++kk)
            aq[kk] = *reinterpret_cast<const s16x8*>(
                &Qb[(size_t)(q0 + wid * 16 + l15) * 64 + kk * 32 + 8 * lhi]);

        f32x4 o_acc[4];
#pragma unroll
        for (int nb = 0; nb < 4; ++nb) o_acc[nb] = (f32x4)0.f;
        float m_r = -1e30f, l_part = 0.f;

        const int nt = qt + 1;

        auto stage = [&](int tt, int bsel) {
#pragma unroll
            for (int i = 0; i < 2; ++i) {
                const int row = 16 * wid + 8 * i + sub;
                const int col16 = c8s ^ (row & 7);
                gload_lds16(&Kb[(size_t)(tt * 64 + row) * 64 + col16 * 8],
                            (char*)&Kbuf[bsel][0] + wid * 2048 + i * 1024);
                gload_lds16(&Vb[(size_t)row * SLEN + tt * 64 + col16 * 8],
                            (char*)&Vbuf[bsel][0] + wid * 2048 + i * 1024);
            }
        };

        stage(0, 0);
        __syncthreads();

        int cur = 0;
#pragma unroll 1
        for (int t = 0; t < nt; ++t) {
            const int kv0 = t * 64;
            if (t + 1 < nt) stage(t + 1, cur ^ 1);

            const unsigned short* KL = Kbuf[cur];
            const unsigned short* VL = Vbuf[cur];

            f32x4 sc2[4];
#pragma unroll
            for (int nb = 0; nb < 4; ++nb) sc2[nb] = (f32x4)0.f;
            __builtin_amdgcn_s_setprio(1);
#pragma unroll
            for (int kk = 0; kk < 2; ++kk) {
                s16x8 ak[4];
#pragma unroll
                for (int nb = 0; nb < 4; ++nb) {
                    const int g = (nb * 16 + l15) * 8 + ((4 * kk + lhi) ^ sK);
                    ak[nb] = *reinterpret_cast<const s16x8*>(&KL[g * 8]);
                }
#pragma unroll
                for (int nb = 0; nb < 4; ++nb)
                    sc2[nb] = __builtin_amdgcn_mfma_f32_16x16x32_bf16(ak[nb], aq[kk], sc2[nb], 0, 0, 0);
            }
            __builtin_amdgcn_s_setprio(0);

            const bool diag = (kv0 + 63 > q0 + wid * 16);
            float tmx = -3e30f;
#pragma unroll
            for (int nb = 0; nb < 4; ++nb)
#pragma unroll
                for (int r = 0; r < 4; ++r) {
                    float x = sc2[nb][r];
                    if (diag && (kv0 + nb * 16 + lhi * 4 + r > qrow)) x = -3e30f;
                    sc2[nb][r] = x;
                    tmx = fmaxf(tmx, x);
                }

            if (__any(tmx - m_r > 64.0f)) {
                float tf = fmaxf(tmx, __shfl_xor(tmx, 16));
                tf = fmaxf(tf, __shfl_xor(tf, 32));
                const float mn = fmaxf(m_r, tf);
                const float alpha = exp2f((m_r - mn) * EXPC);
                m_r = mn;
                l_part *= alpha;
                float ar[4];
#pragma unroll
                for (int r = 0; r < 4; ++r) ar[r] = __shfl(alpha, lhi * 4 + r);
#pragma unroll
                for (int nb = 0; nb < 4; ++nb)
#pragma unroll
                    for (int r = 0; r < 4; ++r) o_acc[nb][r] *= ar[r];
            }

            const float negmC = -m_r * EXPC;
            unsigned short* Pw = &Psm[wid][0];
#pragma unroll
            for (int nb = 0; nb < 4; ++nb) {
                float p0 = exp2f(fmaf(sc2[nb][0], EXPC, negmC));
                float p1 = exp2f(fmaf(sc2[nb][1], EXPC, negmC));
                float p2 = exp2f(fmaf(sc2[nb][2], EXPC, negmC));
                float p3 = exp2f(fmaf(sc2[nb][3], EXPC, negmC));
                l_part += (p0 + p1) + (p2 + p3);
                uint2 u;
                u.x = pack2bf(p0, p1);
                u.y = pack2bf(p2, p3);
                const int g8 = l15 * 16 + ((nb * 4 + lhi) ^ (2 * sK));
                *reinterpret_cast<uint2*>(&Pw[g8 * 4]) = u;
            }

            __builtin_amdgcn_s_setprio(1);
#pragma unroll
            for (int kk = 0; kk < 2; ++kk) {
                const int gp = l15 * 8 + ((4 * kk + lhi) ^ sK);
                s16x8 pa = *reinterpret_cast<const s16x8*>(&Pw[gp * 8]);
                s16x8 bvv[4];
#pragma unroll
                for (int nb = 0; nb < 4; ++nb) {
                    const int g = (nb * 16 + l15) * 8 + ((4 * kk + lhi) ^ sK);
                    bvv[nb] = *reinterpret_cast<const s16x8*>(&VL[g * 8]);
                }
#pragma unroll
                for (int nb = 0; nb < 4; ++nb)
                    o_acc[nb] = __builtin_amdgcn_mfma_f32_16x16x32_bf16(pa, bvv[nb], o_acc[nb], 0, 0, 0);
            }
            __builtin_amdgcn_s_setprio(0);

            __syncthreads();
            cur ^= 1;
        }

        float lf = l_part + __shfl_xor(l_part, 16);
        lf += __shfl_xor(lf, 32);
        float linv[4];
#pragma unroll
        for (int r = 0; r < 4; ++r)
            linv[r] = 1.0f / __shfl(lf, lhi * 4 + r);
#pragma unroll
        for (int nb = 0; nb < 4; ++nb)
#pragma unroll
            for (int r = 0; r < 4; ++r) {
                const int s = q0 + wid * 16 + lhi * 4 + r;
                Ao[((size_t)b * SLEN + s) * DMOD + h * 64 + nb * 16 + l15] =
                    f2bf(o_acc[nb][r] * linv[r]);
            }
        if (seg == 0) __syncthreads();
    }
}

extern "C" void kernel_launch(void* const* d_in, const int* in_sizes, int n_in,
                              void* d_out, int out_size, void* d_ws, size_t ws_size,
                              hipStream_t stream) {
    const float* q  = (const float*)d_in[0];
    const float* k  = (const float*)d_in[1];
    const float* v  = (const float*)d_in[2];
    const float* Wq = (const float*)d_in[4];
    const float* bq = (const float*)d_in[5];
    const float* Wk = (const float*)d_in[6];
    const float* bk = (const float*)d_in[7];
    const float* Wv = (const float*)d_in[8];
    const float* bv = (const float*)d_in[9];
    const float* Wo = (const float*)d_in[10];
    const float* bo = (const float*)d_in[11];

    // ws layout (ushort units). Peak usage 109 MB.
    unsigned short* wsp = (unsigned short*)d_ws;
    unsigned short* qc  = wsp;                    // 8.39M el (bf16 of query)
    unsigned short* kc  = wsp + 8388608;
    unsigned short* vc  = wsp + 16777216;
    unsigned short* wqc = wsp + 25165824;         // 1.05M el each
    unsigned short* wkc = wsp + 26214400;
    unsigned short* wvc = wsp + 27262976;
    unsigned short* woc = wsp + 28311552;
    unsigned short* qb  = wsp + 29360128;         // Q [B,H,S,HD]
    unsigned short* kb  = wsp + 37748736;         // K [B,H,S,HD]
    unsigned short* vtb = wsp + 46137344;         // V^T [B,H,HD,S]
    unsigned short* ao  = qc;                     // alias: qc dead after GEMM-1

    dim3 gb(256);
    convert_bf16<<<dim3(3584), gb, 0, stream>>>(q, k, v, Wq, Wk, Wv, Wo, wsp);
    gemm_bf16<0><<<dim3(512), gb, 0, stream>>>(qc, wqc, bq, qb);
    gemm_bf16<0><<<dim3(512), gb, 0, stream>>>(kc, wkc, bk, kb);
    gemm_bf16<1><<<dim3(512), gb, 0, stream>>>(vc, wvc, bv, vtb);
    attn_kernel<<<dim3(1024), gb, 0, stream>>>(qb, kb, vtb, ao);
    gemm_bf16<2><<<dim3(512), gb, 0, stream>>>(ao, woc, bo, (float*)d_out);
}

// Round 7
// 190.454 us; speedup vs baseline: 2.2872x; 1.0844x over previous
//
#include <hip/hip_runtime.h>
#include <hip/hip_bf16.h>

// B=4, S=2048, D=1024, H=16, HD=64, causal MHA forward, fp32 in/out.
// Pipeline: convert(fp32->bf16) -> 3 proj GEMMs -> flash attn -> out GEMM.

#define SLEN 2048
#define DMOD 1024

typedef __attribute__((ext_vector_type(8))) short s16x8;   // 8 bf16 (4 VGPRs)
typedef __attribute__((ext_vector_type(4))) float f32x4;

__device__ __forceinline__ unsigned short f2bf(float f) {
    union { __hip_bfloat16 h; unsigned short u; } cv;
    cv.h = __float2bfloat16(f);          // native cvt (RNE)
    return cv.u;
}
__device__ __forceinline__ unsigned pack2bf(float a, float b) {
    return (unsigned)f2bf(a) | ((unsigned)f2bf(b) << 16);
}

// async global->LDS, 16B per lane; LDS dest is wave-uniform base + lane*16
__device__ __forceinline__ void gload_lds16(const void* g, void* l) {
    __builtin_amdgcn_global_load_lds(
        (const __attribute__((address_space(1))) void*)g,
        (__attribute__((address_space(3))) void*)l, 16, 0, 0);
}

// ---------------- fp32 -> bf16 convert ----------------
__global__ __launch_bounds__(256) void convert_bf16(
    const float* __restrict__ q, const float* __restrict__ k,
    const float* __restrict__ v, const float* __restrict__ wq,
    const float* __restrict__ wk, const float* __restrict__ wv,
    const float* __restrict__ wo, unsigned short* __restrict__ ws)
{
    const int bid = blockIdx.x, tid = threadIdx.x;
    const float* src;
    unsigned short* dst;
    size_t off;
    if (bid < 3072) {
        const int t = bid >> 10;
        src = (t == 0) ? q : (t == 1) ? k : v;
        dst = ws + (size_t)t * 8388608;
        off = (size_t)(bid & 1023) * 8192;
    } else {
        const int w = (bid - 3072) >> 7;
        src = (w == 0) ? wq : (w == 1) ? wk : (w == 2) ? wv : wo;
        dst = ws + 25165824 + (size_t)w * 1048576;
        off = (size_t)((bid - 3072) & 127) * 8192;
    }
#pragma unroll
    for (int i = 0; i < 8; ++i) {
        const size_t e = off + (size_t)(i * 256 + tid) * 4;
        float4 x = *reinterpret_cast<const float4*>(&src[e]);
        uint2 u;
        u.x = pack2bf(x.x, x.y);
        u.y = pack2bf(x.z, x.w);
        *reinterpret_cast<uint2*>(&dst[e]) = u;
    }
}

// ---------------- bf16 GEMM v3: Y = A @ W^T + bias ----------------
// 128x128 tile, BK=64, 4 waves. Double-buffered LDS + async global_load_lds;
// stage(k+1) issued BEFORE compute(k), ONE barrier per K-step (drain overlaps
// compute). XOR-swizzled (src-side) staging + matching swizzled ds_read.
// MODE 0: bf16 out [B,H,S,HD]  MODE 1: bf16 out [B,H,HD,S]  MODE 2: fp32 [B,S,D]
template<int MODE>
__global__ __launch_bounds__(256) void gemm_bf16(
    const unsigned short* __restrict__ A, const unsigned short* __restrict__ W,
    const float* __restrict__ bias, void* __restrict__ outp)
{
    __shared__ unsigned short Asm[2][8192];   // 16 KB per buffer
    __shared__ unsigned short Bsm[2][8192];

    const int tid  = threadIdx.x;
    const int lane = tid & 63, wid = tid >> 6;
    const int l15 = lane & 15, lhi = lane >> 4;

    // XCD swizzle: 512 blocks, each XCD gets 8 consecutive m-panels (all n).
    const int flat = blockIdx.x;
    const int logical = (flat & 7) * 64 + (flat >> 3);
    const int m0 = (logical >> 3) * 128, n0 = (logical & 7) * 128;

    const int wr = wid >> 1, wc = wid & 1;
    const int srow = lane >> 3;
    const int sgr  = (lane & 7) ^ srow;

    // precomputed swizzled ds_read byte offsets (within one buffer)
    int aoff[2][4], boff[2][4];
#pragma unroll
    for (int kk = 0; kk < 2; ++kk)
#pragma unroll
        for (int i = 0; i < 4; ++i) {
            const int s = ((4 * kk + lhi) ^ (l15 & 7)) * 16;
            aoff[kk][i] = (wr * 64 + i * 16 + l15) * 128 + s;
            boff[kk][i] = (wc * 64 + i * 16 + l15) * 128 + s;
        }

    // lane-local staging source pointers (advance by 64 el per K-step)
    const unsigned short* apt = A + (size_t)(m0 + wid * 8 + srow) * 1024 + sgr * 8;
    const unsigned short* bpt = W + (size_t)(n0 + wid * 8 + srow) * 1024 + sgr * 8;

    f32x4 acc[4][4];
#pragma unroll
    for (int i = 0; i < 4; ++i)
#pragma unroll
        for (int j = 0; j < 4; ++j) acc[i][j] = (f32x4)0.f;

    auto stage = [&](int bsel) {
        char* ad = (char*)Asm + bsel * 16384 + wid * 1024;
        char* bd = (char*)Bsm + bsel * 16384 + wid * 1024;
#pragma unroll
        for (int i = 0; i < 4; ++i) {           // i covers 32 rows each
            gload_lds16(apt + i * 32768, ad + i * 4096);
            gload_lds16(bpt + i * 32768, bd + i * 4096);
        }
        apt += 64; bpt += 64;
    };

    stage(0);
    __syncthreads();
    int cur = 0;
#pragma unroll 1
    for (int kt = 0; kt < 16; ++kt) {
        if (kt < 15) stage(cur ^ 1);            // async, overlaps compute below
        const char* AB = (const char*)Asm + cur * 16384;
        const char* BB = (const char*)Bsm + cur * 16384;
#pragma unroll
        for (int kk = 0; kk < 2; ++kk) {
            s16x8 af[4], bfv[4];
#pragma unroll
            for (int i = 0; i < 4; ++i) af[i]  = *reinterpret_cast<const s16x8*>(AB + aoff[kk][i]);
#pragma unroll
            for (int j = 0; j < 4; ++j) bfv[j] = *reinterpret_cast<const s16x8*>(BB + boff[kk][j]);
#pragma unroll
            for (int i = 0; i < 4; ++i)
#pragma unroll
                for (int j = 0; j < 4; ++j)
                    acc[i][j] = __builtin_amdgcn_mfma_f32_16x16x32_bf16(af[i], bfv[j], acc[i][j], 0, 0, 0);
        }
        __syncthreads();                        // drains DMA + protects reads
        cur ^= 1;
    }

    // epilogue: C/D layout col=lane&15, row=(lane>>4)*4+reg
#pragma unroll
    for (int j = 0; j < 4; ++j) {
        const int col = n0 + wc * 64 + j * 16 + l15;
        const float bv = bias[col];
#pragma unroll
        for (int i = 0; i < 4; ++i) {
#pragma unroll
            for (int r = 0; r < 4; ++r) {
                const int row = m0 + wr * 64 + i * 16 + lhi * 4 + r;
                const float val = acc[i][j][r] + bv;
                if constexpr (MODE == 2) {
                    ((float*)outp)[(size_t)row * 1024 + col] = val;
                } else if constexpr (MODE == 0) {
                    ((unsigned short*)outp)[(size_t)((row >> 11) * 16 + (col >> 6)) * 131072
                                            + (size_t)(row & 2047) * 64 + (col & 63)] = f2bf(val);
                } else {
                    ((unsigned short*)outp)[(size_t)((row >> 11) * 16 + (col >> 6)) * 131072
                                            + (size_t)(col & 63) * 2048 + (row & 2047)] = f2bf(val);
                }
            }
        }
    }
}

// ---------------- flash attention v6 ----------------
// Same algorithm as v5; addressing hoisted out of the k-loop, t-loop split
// into mask-free fast path (t<qt) + diagonal tile (t==qt, block-uniform).
#define EXPC 0.18033688011112043f   // 0.125 * log2(e)

__global__ __launch_bounds__(256, 4) void attn_kernel(
    const unsigned short* __restrict__ Q,
    const unsigned short* __restrict__ Kc,
    const unsigned short* __restrict__ Vt,
    unsigned short* __restrict__ Ao)
{
    __shared__ unsigned short Kbuf[2][4096];   // [64 kv][64 d] swizzled
    __shared__ unsigned short Vbuf[2][4096];   // [64 d][64 kv] swizzled
    __shared__ unsigned short Psm[4][1024];    // per-wave [16 q][64 kv] swizzled

    const int tid = threadIdx.x, lane = tid & 63, wid = tid >> 6;
    const int l15 = lane & 15, lhi = lane >> 4;
    const int sK = l15 & 7;
    const int sub = lane >> 3, c8s = lane & 7;
    const int thr = wid * 16 + l15;            // causal threshold (q0 cancels)

    // precomputed swizzled byte offsets (K and V layouts identical)
    int ko[8], pr[2], pw[4];
#pragma unroll
    for (int kk = 0; kk < 2; ++kk) {
        pr[kk] = (l15 * 8 + ((4 * kk + lhi) ^ sK)) * 16;
#pragma unroll
        for (int nb = 0; nb < 4; ++nb)
            ko[kk * 4 + nb] = ((nb * 16 + l15) * 8 + ((4 * kk + lhi) ^ sK)) * 16;
    }
#pragma unroll
    for (int nb = 0; nb < 4; ++nb)
        pw[nb] = (l15 * 16 + ((nb * 4 + lhi) ^ (2 * sK))) * 8;

    // XCD swizzle: 1024 blocks, flat%8 = XCD, each XCD owns 8 consecutive bh.
    const int flat = blockIdx.x;
    const int logical = (flat & 7) * 128 + (flat >> 3);
    const int bx = logical & 15, bh = logical >> 4;

    const size_t base = (size_t)bh * SLEN * 64;
    const unsigned short* Qb = Q + base;
    const unsigned short* Kb = Kc + base;
    const unsigned short* Vb = Vt + base;      // [64][SLEN]
    const int b = bh >> 4, h = bh & 15;
    const int scol = (c8s ^ sub) * 8;          // pre-swizzled source granule

#pragma unroll 1
    for (int seg = 0; seg < 2; ++seg) {
        const int qt = seg ? (31 - bx) : bx;
        const int q0 = qt * 64;

        s16x8 aq[2];
#pragma unroll
        for (int kk = 0; kk < 2; ++kk)
            aq[kk] = *reinterpret_cast<const s16x8*>(
                &Qb[(size_t)(q0 + wid * 16 + l15) * 64 + kk * 32 + 8 * lhi]);

        f32x4 o_acc[4];
#pragma unroll
        for (int nb = 0; nb < 4; ++nb) o_acc[nb] = (f32x4)0.f;
        float m_r = -1e30f, l_part = 0.f;

        // lane-local staging source pointers, advanced by constants per tile
        const unsigned short* kpt = Kb + (16 * wid + sub) * 64 + scol;
        const unsigned short* vpt = Vb + (size_t)(16 * wid + sub) * SLEN + scol;

        auto stage = [&](int bsel) {
            char* kd = (char*)Kbuf + bsel * 8192 + wid * 2048;
            char* vd = (char*)Vbuf + bsel * 8192 + wid * 2048;
            gload_lds16(kpt,         kd);
            gload_lds16(kpt + 512,   kd + 1024);
            gload_lds16(vpt,         vd);
            gload_lds16(vpt + 16384, vd + 1024);
            kpt += 4096; vpt += 64;
        };

        // one tile of online-softmax attention from buffer at byte-offset cbo
        auto tile = [&](int cbo, bool domask) {
            const char* KB = (const char*)Kbuf + cbo;
            const char* VB = (const char*)Vbuf + cbo;
            char* PW = (char*)Psm + wid * 2048;

            f32x4 sc2[4];
#pragma unroll
            for (int nb = 0; nb < 4; ++nb) sc2[nb] = (f32x4)0.f;
            __builtin_amdgcn_s_setprio(1);
#pragma unroll
            for (int kk = 0; kk < 2; ++kk) {
                s16x8 ak[4];
#pragma unroll
                for (int nb = 0; nb < 4; ++nb)
                    ak[nb] = *reinterpret_cast<const s16x8*>(KB + ko[kk * 4 + nb]);
#pragma unroll
                for (int nb = 0; nb < 4; ++nb)
                    sc2[nb] = __builtin_amdgcn_mfma_f32_16x16x32_bf16(ak[nb], aq[kk], sc2[nb], 0, 0, 0);
            }
            __builtin_amdgcn_s_setprio(0);

            float tmx = -3e30f;
#pragma unroll
            for (int nb = 0; nb < 4; ++nb)
#pragma unroll
                for (int r = 0; r < 4; ++r) {
                    float x = sc2[nb][r];
                    if (domask && (nb * 16 + lhi * 4 + r > thr)) x = -3e30f;
                    sc2[nb][r] = x;
                    tmx = fmaxf(tmx, x);
                }

            if (__any(tmx - m_r > 64.0f)) {      // rare rescale
                float tf = fmaxf(tmx, __shfl_xor(tmx, 16));
                tf = fmaxf(tf, __shfl_xor(tf, 32));
                const float mn = fmaxf(m_r, tf);
                const float alpha = exp2f((m_r - mn) * EXPC);
                m_r = mn;
                l_part *= alpha;
                float ar[4];
#pragma unroll
                for (int r = 0; r < 4; ++r) ar[r] = __shfl(alpha, lhi * 4 + r);
#pragma unroll
                for (int nb = 0; nb < 4; ++nb)
#pragma unroll
                    for (int r = 0; r < 4; ++r) o_acc[nb][r] *= ar[r];
            }

            const float negmC = -m_r * EXPC;
#pragma unroll
            for (int nb = 0; nb < 4; ++nb) {
                float p0 = exp2f(fmaf(sc2[nb][0], EXPC, negmC));
                float p1 = exp2f(fmaf(sc2[nb][1], EXPC, negmC));
                float p2 = exp2f(fmaf(sc2[nb][2], EXPC, negmC));
                float p3 = exp2f(fmaf(sc2[nb][3], EXPC, negmC));
                l_part += (p0 + p1) + (p2 + p3);
                uint2 u;
                u.x = pack2bf(p0, p1);
                u.y = pack2bf(p2, p3);
                *reinterpret_cast<uint2*>(PW + pw[nb]) = u;
            }

            __builtin_amdgcn_s_setprio(1);
#pragma unroll
            for (int kk = 0; kk < 2; ++kk) {
                s16x8 pa = *reinterpret_cast<const s16x8*>(PW + pr[kk]);
                s16x8 bvv[4];
#pragma unroll
                for (int nb = 0; nb < 4; ++nb)
                    bvv[nb] = *reinterpret_cast<const s16x8*>(VB + ko[kk * 4 + nb]);
#pragma unroll
                for (int nb = 0; nb < 4; ++nb)
                    o_acc[nb] = __builtin_amdgcn_mfma_f32_16x16x32_bf16(pa, bvv[nb], o_acc[nb], 0, 0, 0);
            }
            __builtin_amdgcn_s_setprio(0);
        };

        stage(0);
        __syncthreads();
        int cur = 0;

        // fast tiles 0..qt-1 (mask-free, prefetch next)
#pragma unroll 1
        for (int t = 0; t < qt; ++t) {
            stage(cur ^ 1);
            tile(cur * 8192, false);
            __syncthreads();
            cur ^= 1;
        }
        // diagonal tile t == qt
        tile(cur * 8192, true);

        // ---- epilogue: reduce l once, then out[b,s,h*64+d] = o/l ----
        float lf = l_part + __shfl_xor(l_part, 16);
        lf += __shfl_xor(lf, 32);
        float linv[4];
#pragma unroll
        for (int r = 0; r < 4; ++r)
            linv[r] = 1.0f / __shfl(lf, lhi * 4 + r);
#pragma unroll
        for (int nb = 0; nb < 4; ++nb)
#pragma unroll
            for (int r = 0; r < 4; ++r) {
                const int s = q0 + wid * 16 + lhi * 4 + r;
                Ao[((size_t)b * SLEN + s) * DMOD + h * 64 + nb * 16 + l15] =
                    f2bf(o_acc[nb][r] * linv[r]);
            }
        __syncthreads();   // protect buffers before next segment's stage
    }
}

extern "C" void kernel_launch(void* const* d_in, const int* in_sizes, int n_in,
                              void* d_out, int out_size, void* d_ws, size_t ws_size,
                              hipStream_t stream) {
    const float* q  = (const float*)d_in[0];
    const float* k  = (const float*)d_in[1];
    const float* v  = (const float*)d_in[2];
    const float* Wq = (const float*)d_in[4];
    const float* bq = (const float*)d_in[5];
    const float* Wk = (const float*)d_in[6];
    const float* bk = (const float*)d_in[7];
    const float* Wv = (const float*)d_in[8];
    const float* bv = (const float*)d_in[9];
    const float* Wo = (const float*)d_in[10];
    const float* bo = (const float*)d_in[11];

    // ws layout (ushort units). Peak usage 109 MB.
    unsigned short* wsp = (unsigned short*)d_ws;
    unsigned short* qc  = wsp;
    unsigned short* kc  = wsp + 8388608;
    unsigned short* vc  = wsp + 16777216;
    unsigned short* wqc = wsp + 25165824;
    unsigned short* wkc = wsp + 26214400;
    unsigned short* wvc = wsp + 27262976;
    unsigned short* woc = wsp + 28311552;
    unsigned short* qb  = wsp + 29360128;
    unsigned short* kb  = wsp + 37748736;
    unsigned short* vtb = wsp + 46137344;
    unsigned short* ao  = qc;                  // alias: qc dead after GEMM-1

    dim3 gb(256);
    convert_bf16<<<dim3(3584), gb, 0, stream>>>(q, k, v, Wq, Wk, Wv, Wo, wsp);
    gemm_bf16<0><<<dim3(512), gb, 0, stream>>>(qc, wqc, bq, qb);
    gemm_bf16<0><<<dim3(512), gb, 0, stream>>>(kc, wkc, bk, kb);
    gemm_bf16<1><<<dim3(512), gb, 0, stream>>>(vc, wvc, bv, vtb);
    attn_kernel<<<dim3(1024), gb, 0, stream>>>(qb, kb, vtb, ao);
    gemm_bf16<2><<<dim3(512), gb, 0, stream>>>(ao, woc, bo, (float*)d_out);
}

// Round 8
// 187.992 us; speedup vs baseline: 2.3172x; 1.0131x over previous
//
#include <hip/hip_runtime.h>
#include <hip/hip_bf16.h>

// B=4, S=2048, D=1024, H=16, HD=64, causal MHA forward, fp32 in/out.
// Pipeline: convert(fp32->bf16) -> 3 proj GEMMs -> flash attn -> out GEMM.

#define SLEN 2048
#define DMOD 1024

typedef __attribute__((ext_vector_type(8))) short s16x8;   // 8 bf16 (4 VGPRs)
typedef __attribute__((ext_vector_type(4))) float f32x4;

__device__ __forceinline__ unsigned short f2bf(float f) {
    union { __hip_bfloat16 h; unsigned short u; } cv;
    cv.h = __float2bfloat16(f);
    return cv.u;
}
// packed bf16 pair via HW instruction: low16 <- a, high16 <- b (RNE)
__device__ __forceinline__ unsigned cvtpk(float a, float b) {
    unsigned r;
    asm("v_cvt_pk_bf16_f32 %0, %1, %2" : "=v"(r) : "v"(a), "v"(b));
    return r;
}

// async global->LDS, 16B per lane; LDS dest is wave-uniform base + lane*16
__device__ __forceinline__ void gload_lds16(const void* g, void* l) {
    __builtin_amdgcn_global_load_lds(
        (const __attribute__((address_space(1))) void*)g,
        (__attribute__((address_space(3))) void*)l, 16, 0, 0);
}

// ---------------- fp32 -> bf16 convert ----------------
__global__ __launch_bounds__(256) void convert_bf16(
    const float* __restrict__ q, const float* __restrict__ k,
    const float* __restrict__ v, const float* __restrict__ wq,
    const float* __restrict__ wk, const float* __restrict__ wv,
    const float* __restrict__ wo, unsigned short* __restrict__ ws)
{
    const int bid = blockIdx.x, tid = threadIdx.x;
    const float* src;
    unsigned short* dst;
    size_t off;
    if (bid < 3072) {
        const int t = bid >> 10;
        src = (t == 0) ? q : (t == 1) ? k : v;
        dst = ws + (size_t)t * 8388608;
        off = (size_t)(bid & 1023) * 8192;
    } else {
        const int w = (bid - 3072) >> 7;
        src = (w == 0) ? wq : (w == 1) ? wk : (w == 2) ? wv : wo;
        dst = ws + 25165824 + (size_t)w * 1048576;
        off = (size_t)((bid - 3072) & 127) * 8192;
    }
#pragma unroll
    for (int i = 0; i < 8; ++i) {
        const size_t e = off + (size_t)(i * 256 + tid) * 4;
        float4 x = *reinterpret_cast<const float4*>(&src[e]);
        uint2 u;
        u.x = cvtpk(x.x, x.y);
        u.y = cvtpk(x.z, x.w);
        *reinterpret_cast<uint2*>(&dst[e]) = u;
    }
}

// ---------------- bf16 GEMM v3: Y = A @ W^T + bias ----------------
// 128x128 tile, BK=64, 4 waves. Double-buffered LDS + async global_load_lds;
// stage(k+1) issued BEFORE compute(k), ONE barrier per K-step.
// MODE 0: bf16 out [B,H,S,HD]  MODE 1: bf16 out [B,H,HD,S]  MODE 2: fp32 [B,S,D]
template<int MODE>
__global__ __launch_bounds__(256) void gemm_bf16(
    const unsigned short* __restrict__ A, const unsigned short* __restrict__ W,
    const float* __restrict__ bias, void* __restrict__ outp)
{
    __shared__ unsigned short Asm[2][8192];
    __shared__ unsigned short Bsm[2][8192];

    const int tid  = threadIdx.x;
    const int lane = tid & 63, wid = tid >> 6;
    const int l15 = lane & 15, lhi = lane >> 4;

    const int flat = blockIdx.x;
    const int logical = (flat & 7) * 64 + (flat >> 3);
    const int m0 = (logical >> 3) * 128, n0 = (logical & 7) * 128;

    const int wr = wid >> 1, wc = wid & 1;
    const int srow = lane >> 3;
    const int sgr  = (lane & 7) ^ srow;

    int aoff[2][4], boff[2][4];
#pragma unroll
    for (int kk = 0; kk < 2; ++kk)
#pragma unroll
        for (int i = 0; i < 4; ++i) {
            const int s = ((4 * kk + lhi) ^ (l15 & 7)) * 16;
            aoff[kk][i] = (wr * 64 + i * 16 + l15) * 128 + s;
            boff[kk][i] = (wc * 64 + i * 16 + l15) * 128 + s;
        }

    const unsigned short* apt = A + (size_t)(m0 + wid * 8 + srow) * 1024 + sgr * 8;
    const unsigned short* bpt = W + (size_t)(n0 + wid * 8 + srow) * 1024 + sgr * 8;

    f32x4 acc[4][4];
#pragma unroll
    for (int i = 0; i < 4; ++i)
#pragma unroll
        for (int j = 0; j < 4; ++j) acc[i][j] = (f32x4)0.f;

    auto stage = [&](int bsel) {
        char* ad = (char*)Asm + bsel * 16384 + wid * 1024;
        char* bd = (char*)Bsm + bsel * 16384 + wid * 1024;
#pragma unroll
        for (int i = 0; i < 4; ++i) {
            gload_lds16(apt + i * 32768, ad + i * 4096);
            gload_lds16(bpt + i * 32768, bd + i * 4096);
        }
        apt += 64; bpt += 64;
    };

    stage(0);
    __syncthreads();
    int cur = 0;
#pragma unroll 1
    for (int kt = 0; kt < 16; ++kt) {
        if (kt < 15) stage(cur ^ 1);
        const char* AB = (const char*)Asm + cur * 16384;
        const char* BB = (const char*)Bsm + cur * 16384;
#pragma unroll
        for (int kk = 0; kk < 2; ++kk) {
            s16x8 af[4], bfv[4];
#pragma unroll
            for (int i = 0; i < 4; ++i) af[i]  = *reinterpret_cast<const s16x8*>(AB + aoff[kk][i]);
#pragma unroll
            for (int j = 0; j < 4; ++j) bfv[j] = *reinterpret_cast<const s16x8*>(BB + boff[kk][j]);
#pragma unroll
            for (int i = 0; i < 4; ++i)
#pragma unroll
                for (int j = 0; j < 4; ++j)
                    acc[i][j] = __builtin_amdgcn_mfma_f32_16x16x32_bf16(af[i], bfv[j], acc[i][j], 0, 0, 0);
        }
        __syncthreads();
        cur ^= 1;
    }

#pragma unroll
    for (int j = 0; j < 4; ++j) {
        const int col = n0 + wc * 64 + j * 16 + l15;
        const float bv = bias[col];
#pragma unroll
        for (int i = 0; i < 4; ++i) {
#pragma unroll
            for (int r = 0; r < 4; ++r) {
                const int row = m0 + wr * 64 + i * 16 + lhi * 4 + r;
                const float val = acc[i][j][r] + bv;
                if constexpr (MODE == 2) {
                    ((float*)outp)[(size_t)row * 1024 + col] = val;
                } else if constexpr (MODE == 0) {
                    ((unsigned short*)outp)[(size_t)((row >> 11) * 16 + (col >> 6)) * 131072
                                            + (size_t)(row & 2047) * 64 + (col & 63)] = f2bf(val);
                } else {
                    ((unsigned short*)outp)[(size_t)((row >> 11) * 16 + (col >> 6)) * 131072
                                            + (size_t)(col & 63) * 2048 + (row & 2047)] = f2bf(val);
                }
            }
        }
    }
}

// ---------------- flash attention v7 ----------------
// v6 structure + VALU diet: cvt_pk P-pack, l-sum via ones-MFMA (row layout
// matches o_acc -> zero-shuffle epilogue), persistent zero C-operand.
#define EXPC 0.18033688011112043f   // 0.125 * log2(e)

__global__ __launch_bounds__(256, 4) void attn_kernel(
    const unsigned short* __restrict__ Q,
    const unsigned short* __restrict__ Kc,
    const unsigned short* __restrict__ Vt,
    unsigned short* __restrict__ Ao)
{
    __shared__ unsigned short Kbuf[2][4096];   // [64 kv][64 d] swizzled
    __shared__ unsigned short Vbuf[2][4096];   // [64 d][64 kv] swizzled
    __shared__ unsigned short Psm[4][1024];    // per-wave [16 q][64 kv] swizzled

    const int tid = threadIdx.x, lane = tid & 63, wid = tid >> 6;
    const int l15 = lane & 15, lhi = lane >> 4;
    const int sK = l15 & 7;
    const int sub = lane >> 3, c8s = lane & 7;
    const int thr = wid * 16 + l15;            // causal threshold (q0 cancels)

    int ko[8], pr[2], pw[4];
#pragma unroll
    for (int kk = 0; kk < 2; ++kk) {
        pr[kk] = (l15 * 8 + ((4 * kk + lhi) ^ sK)) * 16;
#pragma unroll
        for (int nb = 0; nb < 4; ++nb)
            ko[kk * 4 + nb] = ((nb * 16 + l15) * 8 + ((4 * kk + lhi) ^ sK)) * 16;
    }
#pragma unroll
    for (int nb = 0; nb < 4; ++nb)
        pw[nb] = (l15 * 16 + ((nb * 4 + lhi) ^ (2 * sK))) * 8;

    const int flat = blockIdx.x;
    const int logical = (flat & 7) * 128 + (flat >> 3);
    const int bx = logical & 15, bh = logical >> 4;

    const size_t base = (size_t)bh * SLEN * 64;
    const unsigned short* Qb = Q + base;
    const unsigned short* Kb = Kc + base;
    const unsigned short* Vb = Vt + base;      // [64][SLEN]
    const int b = bh >> 4, h = bh & 15;
    const int scol = (c8s ^ sub) * 8;

    const f32x4 fzero = (f32x4)0.f;                 // persistent zero C-operand
    const s16x8 onesb = (s16x8)(short)0x3F80;       // bf16 1.0 splat (l-sum B)

#pragma unroll 1
    for (int seg = 0; seg < 2; ++seg) {
        const int qt = seg ? (31 - bx) : bx;
        const int q0 = qt * 64;

        s16x8 aq[2];
#pragma unroll
        for (int kk = 0; kk < 2; ++kk)
            aq[kk] = *reinterpret_cast<const s16x8*>(
                &Qb[(size_t)(q0 + wid * 16 + l15) * 64 + kk * 32 + 8 * lhi]);

        f32x4 o_acc[4];
#pragma unroll
        for (int nb = 0; nb < 4; ++nb) o_acc[nb] = (f32x4)0.f;
        f32x4 l_acc = (f32x4)0.f;                   // per-row l, rows = 4*lhi+r
        float m_r = -1e30f;

        const unsigned short* kpt = Kb + (16 * wid + sub) * 64 + scol;
        const unsigned short* vpt = Vb + (size_t)(16 * wid + sub) * SLEN + scol;

        auto stage = [&](int bsel) {
            char* kd = (char*)Kbuf + bsel * 8192 + wid * 2048;
            char* vd = (char*)Vbuf + bsel * 8192 + wid * 2048;
            gload_lds16(kpt,         kd);
            gload_lds16(kpt + 512,   kd + 1024);
            gload_lds16(vpt,         vd);
            gload_lds16(vpt + 16384, vd + 1024);
            kpt += 4096; vpt += 64;
        };

        auto tile = [&](int cbo, bool domask) {
            const char* KB = (const char*)Kbuf + cbo;
            const char* VB = (const char*)Vbuf + cbo;
            char* PW = (char*)Psm + wid * 2048;

            f32x4 sc2[4];
            __builtin_amdgcn_s_setprio(1);
#pragma unroll
            for (int kk = 0; kk < 2; ++kk) {
                s16x8 ak[4];
#pragma unroll
                for (int nb = 0; nb < 4; ++nb)
                    ak[nb] = *reinterpret_cast<const s16x8*>(KB + ko[kk * 4 + nb]);
#pragma unroll
                for (int nb = 0; nb < 4; ++nb)
                    sc2[nb] = __builtin_amdgcn_mfma_f32_16x16x32_bf16(
                        ak[nb], aq[kk], kk == 0 ? fzero : sc2[nb], 0, 0, 0);
            }
            __builtin_amdgcn_s_setprio(0);

            if (domask) {
#pragma unroll
                for (int nb = 0; nb < 4; ++nb)
#pragma unroll
                    for (int r = 0; r < 4; ++r)
                        if (nb * 16 + lhi * 4 + r > thr) sc2[nb][r] = -3e30f;
            }
            // pairwise max tree (max3-fusable)
            float tm[4];
#pragma unroll
            for (int nb = 0; nb < 4; ++nb)
                tm[nb] = fmaxf(fmaxf(sc2[nb][0], sc2[nb][1]),
                               fmaxf(sc2[nb][2], sc2[nb][3]));
            float tmx = fmaxf(fmaxf(tm[0], tm[1]), fmaxf(tm[2], tm[3]));

            if (__any(tmx - m_r > 64.0f)) {      // rare rescale
                float tf = fmaxf(tmx, __shfl_xor(tmx, 16));
                tf = fmaxf(tf, __shfl_xor(tf, 32));
                const float mn = fmaxf(m_r, tf);
                const float alpha = exp2f((m_r - mn) * EXPC);
                m_r = mn;
                float ar[4];
#pragma unroll
                for (int r = 0; r < 4; ++r) ar[r] = __shfl(alpha, lhi * 4 + r);
#pragma unroll
                for (int r = 0; r < 4; ++r) l_acc[r] *= ar[r];
#pragma unroll
                for (int nb = 0; nb < 4; ++nb)
#pragma unroll
                    for (int r = 0; r < 4; ++r) o_acc[nb][r] *= ar[r];
            }

            const float negmC = -m_r * EXPC;
#pragma unroll
            for (int nb = 0; nb < 4; ++nb) {
                float p0 = exp2f(fmaf(sc2[nb][0], EXPC, negmC));
                float p1 = exp2f(fmaf(sc2[nb][1], EXPC, negmC));
                float p2 = exp2f(fmaf(sc2[nb][2], EXPC, negmC));
                float p3 = exp2f(fmaf(sc2[nb][3], EXPC, negmC));
                uint2 u;
                u.x = cvtpk(p0, p1);
                u.y = cvtpk(p2, p3);
                *reinterpret_cast<uint2*>(PW + pw[nb]) = u;
            }

            __builtin_amdgcn_s_setprio(1);
#pragma unroll
            for (int kk = 0; kk < 2; ++kk) {
                s16x8 pa = *reinterpret_cast<const s16x8*>(PW + pr[kk]);
                s16x8 bvv[4];
#pragma unroll
                for (int nb = 0; nb < 4; ++nb)
                    bvv[nb] = *reinterpret_cast<const s16x8*>(VB + ko[kk * 4 + nb]);
#pragma unroll
                for (int nb = 0; nb < 4; ++nb)
                    o_acc[nb] = __builtin_amdgcn_mfma_f32_16x16x32_bf16(pa, bvv[nb], o_acc[nb], 0, 0, 0);
                l_acc = __builtin_amdgcn_mfma_f32_16x16x32_bf16(pa, onesb, l_acc, 0, 0, 0);
            }
            __builtin_amdgcn_s_setprio(0);
        };

        stage(0);
        __syncthreads();
        int cur = 0;

#pragma unroll 1
        for (int t = 0; t < qt; ++t) {
            stage(cur ^ 1);
            tile(cur * 8192, false);
            __syncthreads();
            cur ^= 1;
        }
        tile(cur * 8192, true);

        // ---- epilogue: zero-shuffle (l_acc rows == o_acc rows) ----
        float linv[4];
#pragma unroll
        for (int r = 0; r < 4; ++r) linv[r] = 1.0f / l_acc[r];
#pragma unroll
        for (int nb = 0; nb < 4; ++nb)
#pragma unroll
            for (int r = 0; r < 4; ++r) {
                const int s = q0 + wid * 16 + lhi * 4 + r;
                Ao[((size_t)b * SLEN + s) * DMOD + h * 64 + nb * 16 + l15] =
                    f2bf(o_acc[nb][r] * linv[r]);
            }
        __syncthreads();   // protect buffers before next segment's stage
    }
}

extern "C" void kernel_launch(void* const* d_in, const int* in_sizes, int n_in,
                              void* d_out, int out_size, void* d_ws, size_t ws_size,
                              hipStream_t stream) {
    const float* q  = (const float*)d_in[0];
    const float* k  = (const float*)d_in[1];
    const float* v  = (const float*)d_in[2];
    const float* Wq = (const float*)d_in[4];
    const float* bq = (const float*)d_in[5];
    const float* Wk = (const float*)d_in[6];
    const float* bk = (const float*)d_in[7];
    const float* Wv = (const float*)d_in[8];
    const float* bv = (const float*)d_in[9];
    const float* Wo = (const float*)d_in[10];
    const float* bo = (const float*)d_in[11];

    unsigned short* wsp = (unsigned short*)d_ws;
    unsigned short* qc  = wsp;
    unsigned short* kc  = wsp + 8388608;
    unsigned short* vc  = wsp + 16777216;
    unsigned short* wqc = wsp + 25165824;
    unsigned short* wkc = wsp + 26214400;
    unsigned short* wvc = wsp + 27262976;
    unsigned short* woc = wsp + 28311552;
    unsigned short* qb  = wsp + 29360128;
    unsigned short* kb  = wsp + 37748736;
    unsigned short* vtb = wsp + 46137344;
    unsigned short* ao  = qc;                  // alias: qc dead after GEMM-1

    dim3 gb(256);
    convert_bf16<<<dim3(3584), gb, 0, stream>>>(q, k, v, Wq, Wk, Wv, Wo, wsp);
    gemm_bf16<0><<<dim3(512), gb, 0, stream>>>(qc, wqc, bq, qb);
    gemm_bf16<0><<<dim3(512), gb, 0, stream>>>(kc, wkc, bk, kb);
    gemm_bf16<1><<<dim3(512), gb, 0, stream>>>(vc, wvc, bv, vtb);
    attn_kernel<<<dim3(1024), gb, 0, stream>>>(qb, kb, vtb, ao);
    gemm_bf16<2><<<dim3(512), gb, 0, stream>>>(ao, woc, bo, (float*)d_out);
}